// Round 1
// baseline (1894.282 us; speedup 1.0000x reference)
//
#include <hip/hip_runtime.h>
#include <hip/hip_bf16.h>

#define B_ 2
#define S_ 2048
#define E_ 1024
#define H_ 16
#define D_ 64
#define NE_ 8
#define TOKENS (B_*S_)   // 4096

// ---------------------------------------------------------------------------
// Generic NT GEMM: C[M,N] = A[M,K] @ B[N,K]^T + bias[N] (+ res[M,N] if given)
// 64x64 tile, BK=16, 256 threads, 4x4 micro-tile per thread. M,N,K % 64 == 0.
// ---------------------------------------------------------------------------
__global__ __launch_bounds__(256) void gemm_nt_kernel(
    const float* __restrict__ A, const float* __restrict__ Bw,
    const float* __restrict__ bias, const float* __restrict__ res,
    float* __restrict__ C, int M, int N, int K)
{
    __shared__ __align__(16) float As[16][68];
    __shared__ __align__(16) float Bs[16][68];
    int t  = threadIdx.x;
    int n0 = blockIdx.x * 64;
    int m0 = blockIdx.y * 64;
    int row = t >> 2;          // 0..63
    int kq  = (t & 3) * 4;     // 0,4,8,12
    int tx = t & 15, ty = t >> 4;
    float c[4][4] = {};
    for (int k0 = 0; k0 < K; k0 += 16) {
        float4 av = *(const float4*)&A [(size_t)(m0 + row) * K + k0 + kq];
        float4 bv = *(const float4*)&Bw[(size_t)(n0 + row) * K + k0 + kq];
        As[kq+0][row] = av.x; As[kq+1][row] = av.y; As[kq+2][row] = av.z; As[kq+3][row] = av.w;
        Bs[kq+0][row] = bv.x; Bs[kq+1][row] = bv.y; Bs[kq+2][row] = bv.z; Bs[kq+3][row] = bv.w;
        __syncthreads();
        #pragma unroll
        for (int kk = 0; kk < 16; kk++) {
            float4 a = *(const float4*)&As[kk][ty*4];
            float4 b = *(const float4*)&Bs[kk][tx*4];
            float ar[4] = {a.x, a.y, a.z, a.w};
            float br[4] = {b.x, b.y, b.z, b.w};
            #pragma unroll
            for (int ii = 0; ii < 4; ii++)
                #pragma unroll
                for (int jj = 0; jj < 4; jj++)
                    c[ii][jj] += ar[ii] * br[jj];
        }
        __syncthreads();
    }
    #pragma unroll
    for (int ii = 0; ii < 4; ii++) {
        int m = m0 + ty*4 + ii;
        int n = n0 + tx*4;
        float4 bv = *(const float4*)&bias[n];
        float4 o = {c[ii][0]+bv.x, c[ii][1]+bv.y, c[ii][2]+bv.z, c[ii][3]+bv.w};
        if (res) {
            float4 rv = *(const float4*)&res[(size_t)m*N + n];
            o.x += rv.x; o.y += rv.y; o.z += rv.z; o.w += rv.w;
        }
        *(float4*)&C[(size_t)m*N + n] = o;
    }
}

// ---------------------------------------------------------------------------
// RoPE (in-place on q and k). One thread per (token, head, pair j<32).
// ---------------------------------------------------------------------------
__global__ __launch_bounds__(256) void rope_kernel(float* __restrict__ q, float* __restrict__ k)
{
    int tid = blockIdx.x * 256 + threadIdx.x;   // < TOKENS*H_*32
    int j    = tid & 31;
    int h    = (tid >> 5) & (H_-1);
    int srow = tid >> 9;                        // b*S+s, 0..4095
    int s    = srow & (S_-1);
    size_t base = ((size_t)srow * H_ + h) * D_;
    // inv_freq[j] = 10000^(-j/32) = 2^(-j*log2(10000)/32)
    float inv = exp2f(-(float)j * (13.287712379549449f / 32.f));
    float ang = (float)s * inv;
    float sn, cs;
    sincosf(ang, &sn, &cs);
    float q1 = q[base+j], q2 = q[base+j+32];
    q[base+j]    = q1*cs - q2*sn;
    q[base+j+32] = q2*cs + q1*sn;
    float k1 = k[base+j], k2 = k[base+j+32];
    k[base+j]    = k1*cs - k2*sn;
    k[base+j+32] = k2*cs + k1*sn;
}

// ---------------------------------------------------------------------------
// Attention: one block (256 thr) per (b, h, 16-query tile); online softmax
// over 128-key chunks. q,k,v layout (b,s,h,d); attn_out layout (b,s,E).
// ---------------------------------------------------------------------------
__global__ __launch_bounds__(256) void attn_kernel(
    const float* __restrict__ q, const float* __restrict__ k, const float* __restrict__ v,
    float* __restrict__ attn_out)
{
    __shared__ __align__(16) float qs[16][64];
    __shared__ float sc[16][128];
    __shared__ float red[16][16];
    __shared__ float mrow[16], lrow[16], arow[16];
    int t  = threadIdx.x;
    int q0 = blockIdx.x * 16;
    int h  = blockIdx.y;
    int b  = blockIdx.z;
    {
        int qi = t >> 4, dq = (t & 15) * 4;
        *(float4*)&qs[qi][dq] =
            *(const float4*)&q[(((size_t)(b*S_) + q0 + qi) * H_ + h) * D_ + dq];
    }
    if (t < 16) { mrow[t] = -1e30f; lrow[t] = 0.f; }
    float acc[4] = {0.f, 0.f, 0.f, 0.f};
    int d  = t & 63, qg = t >> 6;
    int jl = t & 127, qh = t >> 7;
    __syncthreads();
    for (int c = 0; c < S_/128; c++) {
        int j0 = c * 128;
        // --- scores: thread computes 8 queries x 1 key ---
        const float* kr = &k[(((size_t)(b*S_) + j0 + jl) * H_ + h) * D_];
        float s8[8] = {};
        #pragma unroll
        for (int dv = 0; dv < 16; dv++) {
            float4 kk4 = *(const float4*)&kr[dv*4];
            #pragma unroll
            for (int qq = 0; qq < 8; qq++) {
                float4 q4 = *(const float4*)&qs[qh*8+qq][dv*4];
                s8[qq] += kk4.x*q4.x + kk4.y*q4.y + kk4.z*q4.z + kk4.w*q4.w;
            }
        }
        #pragma unroll
        for (int qq = 0; qq < 8; qq++) sc[qh*8+qq][jl] = s8[qq] * 0.125f;
        __syncthreads();
        // --- row max ---
        int r = t >> 4, part = t & 15;
        float pm = -1e30f;
        #pragma unroll
        for (int i2 = 0; i2 < 8; i2++) pm = fmaxf(pm, sc[r][part*8+i2]);
        red[r][part] = pm;
        __syncthreads();
        if (t < 16) {
            float cm = -1e30f;
            for (int i2 = 0; i2 < 16; i2++) cm = fmaxf(cm, red[t][i2]);
            float m_old = mrow[t], m_new = fmaxf(m_old, cm);
            arow[t] = expf(m_old - m_new);
            mrow[t] = m_new;
        }
        __syncthreads();
        // --- exponentiate + row sum ---
        float mv = mrow[r], ps = 0.f;
        #pragma unroll
        for (int i2 = 0; i2 < 8; i2++) {
            float p = expf(sc[r][part*8+i2] - mv);
            sc[r][part*8+i2] = p;
            ps += p;
        }
        red[r][part] = ps;
        __syncthreads();
        if (t < 16) {
            float sm = 0.f;
            for (int i2 = 0; i2 < 16; i2++) sm += red[t][i2];
            lrow[t] = lrow[t]*arow[t] + sm;
        }
        __syncthreads();
        // --- accumulate O += P @ V ---
        #pragma unroll
        for (int ii = 0; ii < 4; ii++) acc[ii] *= arow[qg*4+ii];
        const float* vr = &v[(((size_t)(b*S_) + j0) * H_ + h) * D_ + d];
        for (int jj = 0; jj < 128; jj++) {
            float vv = vr[(size_t)jj * (H_*D_)];
            #pragma unroll
            for (int ii = 0; ii < 4; ii++) acc[ii] += sc[qg*4+ii][jj] * vv;
        }
        __syncthreads();
    }
    #pragma unroll
    for (int ii = 0; ii < 4; ii++) {
        int qi = qg*4 + ii;
        attn_out[((size_t)(b*S_) + q0 + qi) * E_ + h*D_ + d] = acc[ii] / lrow[qi];
    }
}

// ---------------------------------------------------------------------------
// Gate logits -> softmax -> top2 -> build per-expert token lists.
// One wave per token (4 tokens per block).
// ---------------------------------------------------------------------------
__global__ __launch_bounds__(256) void gate_topk_kernel(
    const float* __restrict__ attn_out, const float* __restrict__ gate_w,
    const float* __restrict__ gate_b, float* __restrict__ gval,
    int* __restrict__ list, int* __restrict__ counts)
{
    int t = threadIdx.x;
    int token = blockIdx.x * 4 + (t >> 6);
    int lane  = t & 63;
    const float* a = attn_out + (size_t)token * E_;
    float part[NE_] = {};
    for (int i = lane; i < E_; i += 64) {
        float av = a[i];
        #pragma unroll
        for (int n = 0; n < NE_; n++) part[n] += av * gate_w[n*E_ + i];
    }
    #pragma unroll
    for (int n = 0; n < NE_; n++) {
        #pragma unroll
        for (int off = 32; off >= 1; off >>= 1)
            part[n] += __shfl_down(part[n], off, 64);
    }
    if (lane == 0) {
        float lg[NE_];
        #pragma unroll
        for (int n = 0; n < NE_; n++) lg[n] = part[n] + gate_b[n];
        float m = lg[0];
        #pragma unroll
        for (int n = 1; n < NE_; n++) m = fmaxf(m, lg[n]);
        float ex[NE_], ssum = 0.f;
        #pragma unroll
        for (int n = 0; n < NE_; n++) { ex[n] = expf(lg[n]-m); ssum += ex[n]; }
        float invs = 1.f / ssum;
        int i0 = 0;
        #pragma unroll
        for (int n = 1; n < NE_; n++) if (lg[n] > lg[i0]) i0 = n;
        int i1 = (i0 == 0) ? 1 : 0;
        #pragma unroll
        for (int n = 0; n < NE_; n++) if (n != i0 && lg[n] > lg[i1]) i1 = n;
        int pos0 = atomicAdd(&counts[i0], 1);
        list[i0*TOKENS + pos0] = token*2;
        gval[token*2] = ex[i0]*invs;
        int pos1 = atomicAdd(&counts[i1], 1);
        list[i1*TOKENS + pos1] = token*2 + 1;
        gval[token*2+1] = ex[i1]*invs;
    }
}

// ---------------------------------------------------------------------------
// Gathered expert GEMM: for expert e, rows = tokens in its list.
// sel_out[entry][n] = gval[entry] * (attn[token] . ew[e][n] + eb[e][n])
// ---------------------------------------------------------------------------
__global__ __launch_bounds__(256) void expert_gemm_kernel(
    const float* __restrict__ attn, const float* __restrict__ ew,
    const float* __restrict__ eb, const int* __restrict__ list,
    const int* __restrict__ counts, const float* __restrict__ gval,
    float* __restrict__ sel_out)
{
    int e   = blockIdx.z;
    int cnt = counts[e];
    int m0  = blockIdx.y * 64;
    if (m0 >= cnt) return;
    __shared__ int rowent[64];
    __shared__ __align__(16) float As[16][68];
    __shared__ __align__(16) float Bs[16][68];
    int t = threadIdx.x;
    if (t < 64) {
        int m = m0 + t;
        rowent[t] = (m < cnt) ? list[e*TOKENS + m] : -1;
    }
    __syncthreads();
    int n0  = blockIdx.x * 64;
    int row = t >> 2, kq = (t & 3) * 4;
    int tx = t & 15, ty = t >> 4;
    int ent = rowent[row];
    const float* ap = &attn[(size_t)((ent >= 0) ? (ent >> 1) : 0) * E_];
    const float* bw = &ew[(size_t)e*E_*E_ + (size_t)(n0 + row)*E_];
    bool valid = (ent >= 0);
    float c[4][4] = {};
    for (int k0 = 0; k0 < E_; k0 += 16) {
        float4 av = valid ? *(const float4*)&ap[k0 + kq] : float4{0.f,0.f,0.f,0.f};
        float4 bv = *(const float4*)&bw[k0 + kq];
        As[kq+0][row] = av.x; As[kq+1][row] = av.y; As[kq+2][row] = av.z; As[kq+3][row] = av.w;
        Bs[kq+0][row] = bv.x; Bs[kq+1][row] = bv.y; Bs[kq+2][row] = bv.z; Bs[kq+3][row] = bv.w;
        __syncthreads();
        #pragma unroll
        for (int kk = 0; kk < 16; kk++) {
            float4 a = *(const float4*)&As[kk][ty*4];
            float4 b = *(const float4*)&Bs[kk][tx*4];
            float ar[4] = {a.x, a.y, a.z, a.w};
            float br[4] = {b.x, b.y, b.z, b.w};
            #pragma unroll
            for (int ii = 0; ii < 4; ii++)
                #pragma unroll
                for (int jj = 0; jj < 4; jj++)
                    c[ii][jj] += ar[ii] * br[jj];
        }
        __syncthreads();
    }
    #pragma unroll
    for (int ii = 0; ii < 4; ii++) {
        int m = m0 + ty*4 + ii;
        if (m >= cnt) continue;
        int ent2 = rowent[ty*4 + ii];
        float g = gval[ent2];
        int n = n0 + tx*4;
        float4 bb = *(const float4*)&eb[e*E_ + n];
        float4 o = {(c[ii][0]+bb.x)*g, (c[ii][1]+bb.y)*g,
                    (c[ii][2]+bb.z)*g, (c[ii][3]+bb.w)*g};
        *(float4*)&sel_out[(size_t)ent2 * E_ + n] = o;
    }
}

// ---------------------------------------------------------------------------
// moe[token][n] = sel[token][0][n] + sel[token][1][n]
// ---------------------------------------------------------------------------
__global__ __launch_bounds__(256) void combine_kernel(
    const float* __restrict__ sel, float* __restrict__ moe)
{
    int idx = blockIdx.x * 256 + threadIdx.x;
    int token = idx >> 10;
    int n = idx & (E_-1);
    moe[idx] = sel[(size_t)token*2*E_ + n] + sel[(size_t)token*2*E_ + E_ + n];
}

// ---------------------------------------------------------------------------
extern "C" void kernel_launch(void* const* d_in, const int* in_sizes, int n_in,
                              void* d_out, int out_size, void* d_ws, size_t ws_size,
                              hipStream_t stream) {
    const float* x      = (const float*)d_in[0];
    const float* q_w    = (const float*)d_in[1];
    const float* q_b    = (const float*)d_in[2];
    const float* k_w    = (const float*)d_in[3];
    const float* k_b    = (const float*)d_in[4];
    const float* v_w    = (const float*)d_in[5];
    const float* v_b    = (const float*)d_in[6];
    const float* gate_w = (const float*)d_in[7];
    const float* gate_b = (const float*)d_in[8];
    const float* ew     = (const float*)d_in[9];
    const float* eb     = (const float*)d_in[10];
    const float* ffn_w  = (const float*)d_in[11];
    const float* ffn_b  = (const float*)d_in[12];
    float* out = (float*)d_out;
    float* ws  = (float*)d_ws;

    const size_t NT = (size_t)TOKENS * E_;   // 4,194,304 floats
    float* qb  = ws;            // q; later reused as sel_out (spans qb..kb)
    float* kb  = ws + NT;
    float* vb  = ws + 2*NT;     // v; later reused as moe_out
    float* ab  = ws + 3*NT;     // attn_out
    float* sel = qb;
    float* moe = vb;
    float* gval   = ws + 4*NT;                       // 8192 floats
    int*   list   = (int*)(ws + 4*NT + 2*TOKENS);    // 8*4096 ints
    int*   counts = (int*)(ws + 4*NT + 2*TOKENS + NE_*TOKENS);

    hipMemsetAsync(counts, 0, NE_*sizeof(int), stream);

    dim3 blk(256);
    dim3 gq(E_/64, TOKENS/64);
    gemm_nt_kernel<<<gq, blk, 0, stream>>>(x, q_w, q_b, nullptr, qb, TOKENS, E_, E_);
    gemm_nt_kernel<<<gq, blk, 0, stream>>>(x, k_w, k_b, nullptr, kb, TOKENS, E_, E_);
    gemm_nt_kernel<<<gq, blk, 0, stream>>>(x, v_w, v_b, nullptr, vb, TOKENS, E_, E_);

    rope_kernel<<<(TOKENS*H_*32)/256, blk, 0, stream>>>(qb, kb);

    dim3 ga(S_/16, H_, B_);
    attn_kernel<<<ga, blk, 0, stream>>>(qb, kb, vb, ab);

    gate_topk_kernel<<<TOKENS/4, blk, 0, stream>>>(ab, gate_w, gate_b, gval, list, counts);

    dim3 ge(E_/64, TOKENS/64, NE_);
    expert_gemm_kernel<<<ge, blk, 0, stream>>>(ab, ew, eb, list, counts, gval, sel);

    combine_kernel<<<(TOKENS*E_)/256, blk, 0, stream>>>(sel, moe);

    gemm_nt_kernel<<<gq, blk, 0, stream>>>(moe, ffn_w, ffn_b, x, out, TOKENS, E_, E_);
}

// Round 2
// 699.123 us; speedup vs baseline: 2.7095x; 2.7095x over previous
//
#include <hip/hip_runtime.h>
#include <hip/hip_bf16.h>

#define B_ 2
#define S_ 2048
#define E_ 1024
#define H_ 16
#define D_ 64
#define NE_ 8
#define TOKENS (B_*S_)   // 4096

typedef __attribute__((ext_vector_type(8))) short bf16x8;
typedef __attribute__((ext_vector_type(4))) float f32x4;
typedef unsigned short u16;
typedef unsigned int u32;

__device__ __forceinline__ u16 f2bf(float f) {
    u32 u = __float_as_uint(f);
    u32 r = u + 0x7fffu + ((u >> 16) & 1u);
    return (u16)(r >> 16);
}
__device__ __forceinline__ float bf2f(u16 h) {
    return __uint_as_float(((u32)h) << 16);
}
__device__ __forceinline__ void gl2lds16(const void* g, void* l) {
    __builtin_amdgcn_global_load_lds(
        (__attribute__((address_space(1))) void*)(g),
        (__attribute__((address_space(3))) void*)(l), 16, 0, 0);
}
#define MFMA16(a,b,c) __builtin_amdgcn_mfma_f32_16x16x32_bf16(a,b,c,0,0,0)

// ---------------------------------------------------------------------------
// fp32 split into bf16 hi/lo  (x, q_w, k_w)
// ---------------------------------------------------------------------------
__global__ void cvt_split_k(const float* __restrict__ s, u16* __restrict__ h,
                            u16* __restrict__ l, int n4)
{
    const int i = blockIdx.x * 256 + threadIdx.x;
    if (i >= n4) return;
    const float4 v = *(const float4*)(s + (size_t)i * 4);
    const float x[4] = {v.x, v.y, v.z, v.w};
    u16 hh[4], ll[4];
    #pragma unroll
    for (int j = 0; j < 4; j++) {
        hh[j] = f2bf(x[j]);
        ll[j] = f2bf(x[j] - bf2f(hh[j]));
    }
    ushort4 H = {hh[0], hh[1], hh[2], hh[3]};
    ushort4 L = {ll[0], ll[1], ll[2], ll[3]};
    *(ushort4*)(h + (size_t)i * 4) = H;
    *(ushort4*)(l + (size_t)i * 4) = L;
}

__global__ void cvt_plain_k(const float* __restrict__ s, u16* __restrict__ h, int n4)
{
    const int i = blockIdx.x * 256 + threadIdx.x;
    if (i >= n4) return;
    const float4 v = *(const float4*)(s + (size_t)i * 4);
    ushort4 H = {f2bf(v.x), f2bf(v.y), f2bf(v.z), f2bf(v.w)};
    *(ushort4*)(h + (size_t)i * 4) = H;
}

// ---------------------------------------------------------------------------
// Mf[h*8+e][i] = sum_d gate_w[e][h*64+d] * v_w[h*64+d][i]   (fp32, exact gate path)
// c0[e] += sum_d gate_w[e][h*64+d] * v_b[h*64+d]
// ---------------------------------------------------------------------------
__global__ void gwvw_kernel(const float* __restrict__ gw, const float* __restrict__ vw,
                            const float* __restrict__ vb, float* __restrict__ Mf,
                            float* __restrict__ c0)
{
    const int h = blockIdx.y;
    const int i = blockIdx.x * 256 + threadIdx.x;   // grid.x = 4
    float acc[8] = {};
    for (int d = 0; d < 64; d++) {
        const float v = vw[(size_t)(h * 64 + d) * E_ + i];
        #pragma unroll
        for (int e = 0; e < 8; e++) acc[e] += v * gw[e * E_ + h * 64 + d];
    }
    #pragma unroll
    for (int e = 0; e < 8; e++) Mf[(size_t)(h * 8 + e) * E_ + i] = acc[e];
    if (blockIdx.x == 0 && threadIdx.x < 8) {
        float s = 0.f;
        for (int d = 0; d < 64; d++)
            s += gw[threadIdx.x * E_ + h * 64 + d] * vb[h * 64 + d];
        atomicAdd(&c0[threadIdx.x], s);
    }
}

// ---------------------------------------------------------------------------
// fp32 NT GEMM (round-1 kernel, nullable bias/res) — used for vg = x @ Mf^T
// ---------------------------------------------------------------------------
__global__ __launch_bounds__(256) void gemm_nt_kernel(
    const float* __restrict__ A, const float* __restrict__ Bw,
    const float* __restrict__ bias, const float* __restrict__ res,
    float* __restrict__ C, int M, int N, int K)
{
    __shared__ __align__(16) float As[16][68];
    __shared__ __align__(16) float Bs[16][68];
    int t  = threadIdx.x;
    int n0 = blockIdx.x * 64;
    int m0 = blockIdx.y * 64;
    int row = t >> 2;
    int kq  = (t & 3) * 4;
    int tx = t & 15, ty = t >> 4;
    float c[4][4] = {};
    for (int k0 = 0; k0 < K; k0 += 16) {
        float4 av = *(const float4*)&A [(size_t)(m0 + row) * K + k0 + kq];
        float4 bv = *(const float4*)&Bw[(size_t)(n0 + row) * K + k0 + kq];
        As[kq+0][row] = av.x; As[kq+1][row] = av.y; As[kq+2][row] = av.z; As[kq+3][row] = av.w;
        Bs[kq+0][row] = bv.x; Bs[kq+1][row] = bv.y; Bs[kq+2][row] = bv.z; Bs[kq+3][row] = bv.w;
        __syncthreads();
        #pragma unroll
        for (int kk = 0; kk < 16; kk++) {
            float4 a = *(const float4*)&As[kk][ty*4];
            float4 b = *(const float4*)&Bs[kk][tx*4];
            float ar[4] = {a.x, a.y, a.z, a.w};
            float br[4] = {b.x, b.y, b.z, b.w};
            #pragma unroll
            for (int ii = 0; ii < 4; ii++)
                #pragma unroll
                for (int jj = 0; jj < 4; jj++)
                    c[ii][jj] += ar[ii] * br[jj];
        }
        __syncthreads();
    }
    #pragma unroll
    for (int ii = 0; ii < 4; ii++) {
        int m = m0 + ty*4 + ii;
        int n = n0 + tx*4;
        float4 o = {c[ii][0], c[ii][1], c[ii][2], c[ii][3]};
        if (bias) {
            float4 bv = *(const float4*)&bias[n];
            o.x += bv.x; o.y += bv.y; o.z += bv.z; o.w += bv.w;
        }
        if (res) {
            float4 rv = *(const float4*)&res[(size_t)m*N + n];
            o.x += rv.x; o.y += rv.y; o.z += rv.z; o.w += rv.w;
        }
        *(float4*)&C[(size_t)m*N + n] = o;
    }
}

// ---------------------------------------------------------------------------
// Split-bf16 3-pass MFMA GEMM (Q/K projections) + fused RoPE epilogue.
// C = (Ah+Al)(Bh+Bl)^T + bias, error ~2^-17 (keeps gate logits flip-free).
// Output written as bf16 hi/lo in head-major layout [b][h][s][d].
// 128x128 tile, BK=32, 4 waves (2x2), 16x16x32 MFMA.
// ---------------------------------------------------------------------------
__global__ __launch_bounds__(256,2) void gemm_qk_rope(
    const u16* __restrict__ Ah, const u16* __restrict__ Al,
    const u16* __restrict__ Bh, const u16* __restrict__ Bl,
    const float* __restrict__ bias,
    u16* __restrict__ Oh, u16* __restrict__ Ol)
{
    __shared__ __align__(16) u16 sAh[128*32], sAl[128*32], sBh[128*32], sBl[128*32];
    const int t = threadIdx.x;
    const int m0 = blockIdx.y * 128, n0 = blockIdx.x * 128;
    const int lane = t & 63, w = t >> 6;
    const int wm = w >> 1, wn = w & 1;
    const int lr = lane & 15, qd = lane >> 4;
    f32x4 acc[4][4] = {};
    const size_t gA = (size_t)(m0 + (t >> 2)) * E_ + (t & 3) * 8;
    const size_t gB = (size_t)(n0 + (t >> 2)) * E_ + (t & 3) * 8;
    for (int k0 = 0; k0 < E_; k0 += 32) {
        #pragma unroll
        for (int is = 0; is < 2; is++) {
            const int ldo = (is * 256 + (t & 192)) * 16;
            const size_t ro = (size_t)is * 64 * E_;
            gl2lds16(Ah + gA + ro + k0, (char*)sAh + ldo);
            gl2lds16(Al + gA + ro + k0, (char*)sAl + ldo);
            gl2lds16(Bh + gB + ro + k0, (char*)sBh + ldo);
            gl2lds16(Bl + gB + ro + k0, (char*)sBl + ldo);
        }
        __syncthreads();
        bf16x8 ah[4], al[4], bh[4], bl[4];
        #pragma unroll
        for (int i = 0; i < 4; i++) {
            ah[i] = *(const bf16x8*)&sAh[(wm*64 + i*16 + lr)*32 + qd*8];
            al[i] = *(const bf16x8*)&sAl[(wm*64 + i*16 + lr)*32 + qd*8];
            bh[i] = *(const bf16x8*)&sBh[(wn*64 + i*16 + lr)*32 + qd*8];
            bl[i] = *(const bf16x8*)&sBl[(wn*64 + i*16 + lr)*32 + qd*8];
        }
        #pragma unroll
        for (int i = 0; i < 4; i++)
            #pragma unroll
            for (int j = 0; j < 4; j++) {
                acc[i][j] = MFMA16(ah[i], bh[j], acc[i][j]);
                acc[i][j] = MFMA16(ah[i], bl[j], acc[i][j]);
                acc[i][j] = MFMA16(al[i], bh[j], acc[i][j]);
            }
        __syncthreads();
    }
    // Epilogue: bias + RoPE + bf16 split + head-major store.
    // Wave's 64 columns == one head; pair (d, d+32) is (subtile j, j+2), same lane.
    const int head = (n0 + wn * 64) >> 6;
    const float C32 = 0.41524101186091903f;   // log2(10000)/32
    #pragma unroll
    for (int j = 0; j < 2; j++) {
        const int d1 = j * 16 + lr;
        const float b1 = bias[head * 64 + d1];
        const float b2 = bias[head * 64 + d1 + 32];
        const float inv = exp2f(-(float)d1 * C32);
        #pragma unroll
        for (int i = 0; i < 4; i++) {
            #pragma unroll
            for (int r = 0; r < 4; r++) {
                const int tok = m0 + wm*64 + i*16 + qd*4 + r;
                const int bb = tok >> 11, ss = tok & (S_ - 1);
                float sn, cs;
                sincosf((float)ss * inv, &sn, &cs);
                const float q1 = acc[i][j][r]   + b1;
                const float q2 = acc[i][j+2][r] + b2;
                const float o1 = q1 * cs - q2 * sn;
                const float o2 = q2 * cs + q1 * sn;
                const size_t o = (((size_t)bb * H_ + head) * S_ + ss) * 64 + d1;
                const u16 h1 = f2bf(o1);
                Oh[o] = h1;       Ol[o] = f2bf(o1 - bf2f(h1));
                const u16 h2 = f2bf(o2);
                Oh[o+32] = h2;    Ol[o+32] = f2bf(o2 - bf2f(h2));
            }
        }
    }
}

// ---------------------------------------------------------------------------
// Plain bf16 GEMM for V projection; epilogue writes transposed bf16 Vt[b][h][d][s].
// ---------------------------------------------------------------------------
__global__ __launch_bounds__(256,2) void gemm_v(
    const u16* __restrict__ Ah, const u16* __restrict__ Bh,
    const float* __restrict__ bias, u16* __restrict__ Vt)
{
    __shared__ __align__(16) u16 sA[128*32], sB[128*32];
    const int t = threadIdx.x;
    const int m0 = blockIdx.y * 128, n0 = blockIdx.x * 128;
    const int lane = t & 63, w = t >> 6;
    const int wm = w >> 1, wn = w & 1;
    const int lr = lane & 15, qd = lane >> 4;
    f32x4 acc[4][4] = {};
    const size_t gA = (size_t)(m0 + (t >> 2)) * E_ + (t & 3) * 8;
    const size_t gB = (size_t)(n0 + (t >> 2)) * E_ + (t & 3) * 8;
    for (int k0 = 0; k0 < E_; k0 += 32) {
        #pragma unroll
        for (int is = 0; is < 2; is++) {
            const int ldo = (is * 256 + (t & 192)) * 16;
            const size_t ro = (size_t)is * 64 * E_;
            gl2lds16(Ah + gA + ro + k0, (char*)sA + ldo);
            gl2lds16(Bh + gB + ro + k0, (char*)sB + ldo);
        }
        __syncthreads();
        bf16x8 af[4], bf[4];
        #pragma unroll
        for (int i = 0; i < 4; i++) {
            af[i] = *(const bf16x8*)&sA[(wm*64 + i*16 + lr)*32 + qd*8];
            bf[i] = *(const bf16x8*)&sB[(wn*64 + i*16 + lr)*32 + qd*8];
        }
        #pragma unroll
        for (int i = 0; i < 4; i++)
            #pragma unroll
            for (int j = 0; j < 4; j++)
                acc[i][j] = MFMA16(af[i], bf[j], acc[i][j]);
        __syncthreads();
    }
    const int head = (n0 + wn * 64) >> 6;
    #pragma unroll
    for (int j = 0; j < 4; j++) {
        const int d = j * 16 + lr;
        const float bv = bias[head * 64 + d];
        #pragma unroll
        for (int i = 0; i < 4; i++)
            #pragma unroll
            for (int r = 0; r < 4; r++) {
                const int tok = m0 + wm*64 + i*16 + qd*4 + r;
                const int bb = tok >> 11, ss = tok & (S_ - 1);
                Vt[(((size_t)bb * H_ + head) * 64 + d) * S_ + ss] = f2bf(acc[i][j][r] + bv);
            }
    }
}

// ---------------------------------------------------------------------------
// Flash attention, split-bf16 QK^T (3-pass, accurate) + plain bf16 PV.
// Accumulates exact fp32 gate-logit partials via vg. Block: (b,h,64 queries).
// ---------------------------------------------------------------------------
__global__ __launch_bounds__(256,2) void attn_kernel(
    const u16* __restrict__ Qh, const u16* __restrict__ Ql,
    const u16* __restrict__ Kh, const u16* __restrict__ Kl,
    const u16* __restrict__ Vt, const float* __restrict__ vg,
    u16* __restrict__ attn_bf, float* __restrict__ plog)
{
    __shared__ __align__(16) u16 sKh[64][72], sKl[64][72], sV[64][72];
    __shared__ __align__(16) float svg[64][8];
    __shared__ __align__(16) u16 sP[4][16][72];
    const int t = threadIdx.x, lane = t & 63, w = t >> 6;
    const int lr = lane & 15, qd = lane >> 4;
    const int q0 = blockIdx.x * 64;
    const int h = blockIdx.y, b = blockIdx.z;
    const size_t bhS = ((size_t)b * H_ + h) * S_;
    bf16x8 qfh0, qfh1, qfl0, qfl1;
    {
        const size_t qa = (bhS + q0 + w * 16 + lr) * 64 + qd * 8;
        qfh0 = *(const bf16x8*)&Qh[qa];
        qfh1 = *(const bf16x8*)&Qh[qa + 32];
        qfl0 = *(const bf16x8*)&Ql[qa];
        qfl1 = *(const bf16x8*)&Ql[qa + 32];
    }
    f32x4 O[4] = {};
    float mrow[4] = {-3e38f, -3e38f, -3e38f, -3e38f};
    float lsum[4] = {};
    float lgp[4][8] = {};
    for (int j0 = 0; j0 < S_; j0 += 64) {
        #pragma unroll
        for (int is = 0; is < 2; is++) {
            const int row = is * 32 + (t >> 3);
            const int c = (t & 7) * 8;
            *(uint4*)&sKh[row][c] = *(const uint4*)&Kh[(bhS + j0 + row) * 64 + c];
            *(uint4*)&sKl[row][c] = *(const uint4*)&Kl[(bhS + j0 + row) * 64 + c];
            *(uint4*)&sV [row][c] = *(const uint4*)&Vt[(((size_t)b*H_ + h)*64 + row) * S_ + j0 + c];
        }
        if (t < 128) {
            const int row = t >> 1, c = (t & 1) * 4;
            *(float4*)&svg[row][c] = *(const float4*)&vg[(size_t)(b*S_ + j0 + row) * 128 + h*8 + c];
        }
        __syncthreads();
        // S = Q K^T (split: qh*kh + qh*kl + ql*kh)
        f32x4 S[4];
        #pragma unroll
        for (int sb = 0; sb < 4; sb++) {
            const int kr = sb * 16 + lr;
            bf16x8 kh0 = *(const bf16x8*)&sKh[kr][qd*8];
            bf16x8 kh1 = *(const bf16x8*)&sKh[kr][32 + qd*8];
            bf16x8 kl0 = *(const bf16x8*)&sKl[kr][qd*8];
            bf16x8 kl1 = *(const bf16x8*)&sKl[kr][32 + qd*8];
            f32x4 a = {};
            a = MFMA16(qfh0, kh0, a);
            a = MFMA16(qfh1, kh1, a);
            a = MFMA16(qfh0, kl0, a);
            a = MFMA16(qfh1, kl1, a);
            a = MFMA16(qfl0, kh0, a);
            a = MFMA16(qfl1, kh1, a);
            S[sb] = a;
        }
        // online softmax; row r lives at q = qd*4+r, cols on lanes (lr)
        float alpha[4];
        #pragma unroll
        for (int r = 0; r < 4; r++) {
            float mx = fmaxf(fmaxf(S[0][r], S[1][r]), fmaxf(S[2][r], S[3][r])) * 0.125f;
            #pragma unroll
            for (int d = 1; d < 16; d <<= 1)
                mx = fmaxf(mx, __shfl_xor(mx, d, 64));
            const float mn = fmaxf(mrow[r], mx);
            alpha[r] = __expf(mrow[r] - mn);
            mrow[r] = mn;
        }
        float P[4][4];
        float ps[4] = {};
        #pragma unroll
        for (int sb = 0; sb < 4; sb++)
            #pragma unroll
            for (int r = 0; r < 4; r++) {
                const float p = __expf(S[sb][r] * 0.125f - mrow[r]);
                P[sb][r] = p;
                ps[r] += p;
            }
        #pragma unroll
        for (int r = 0; r < 4; r++) {
            float s2 = ps[r];
            #pragma unroll
            for (int d = 1; d < 16; d <<= 1) s2 += __shfl_xor(s2, d, 64);
            lsum[r] = lsum[r] * alpha[r] + s2;
        }
        // exact fp32 gate-logit partials
        #pragma unroll
        for (int r = 0; r < 4; r++)
            #pragma unroll
            for (int e = 0; e < 8; e++) lgp[r][e] *= alpha[r];
        #pragma unroll
        for (int sb = 0; sb < 4; sb++) {
            const float4 g0 = *(const float4*)&svg[sb*16 + lr][0];
            const float4 g1 = *(const float4*)&svg[sb*16 + lr][4];
            #pragma unroll
            for (int r = 0; r < 4; r++) {
                const float p = P[sb][r];
                lgp[r][0] += p * g0.x; lgp[r][1] += p * g0.y;
                lgp[r][2] += p * g0.z; lgp[r][3] += p * g0.w;
                lgp[r][4] += p * g1.x; lgp[r][5] += p * g1.y;
                lgp[r][6] += p * g1.z; lgp[r][7] += p * g1.w;
            }
        }
        // P -> LDS (C-layout to A-layout transform), O rescale, PV
        #pragma unroll
        for (int sb = 0; sb < 4; sb++)
            #pragma unroll
            for (int r = 0; r < 4; r++)
                sP[w][qd*4 + r][sb*16 + lr] = f2bf(P[sb][r]);
        #pragma unroll
        for (int r = 0; r < 4; r++) {
            O[0][r] *= alpha[r]; O[1][r] *= alpha[r];
            O[2][r] *= alpha[r]; O[3][r] *= alpha[r];
        }
        bf16x8 p0 = *(const bf16x8*)&sP[w][lr][qd*8];
        bf16x8 p1 = *(const bf16x8*)&sP[w][lr][32 + qd*8];
        #pragma unroll
        for (int ds = 0; ds < 4; ds++) {
            bf16x8 v0 = *(const bf16x8*)&sV[ds*16 + lr][qd*8];
            bf16x8 v1 = *(const bf16x8*)&sV[ds*16 + lr][32 + qd*8];
            O[ds] = MFMA16(p0, v0, O[ds]);
            O[ds] = MFMA16(p1, v1, O[ds]);
        }
        __syncthreads();
    }
    // epilogue: attn_out bf16 [tok][E]
    #pragma unroll
    for (int ds = 0; ds < 4; ds++)
        #pragma unroll
        for (int r = 0; r < 4; r++) {
            const int q = q0 + w * 16 + qd * 4 + r;
            attn_bf[(size_t)(b * S_ + q) * E_ + h * 64 + ds * 16 + lr] = f2bf(O[ds][r] / lsum[r]);
        }
    // reduce logit partials across 16 lanes, store per-head logits
    #pragma unroll
    for (int r = 0; r < 4; r++)
        #pragma unroll
        for (int e = 0; e < 8; e++) {
            float s2 = lgp[r][e];
            #pragma unroll
            for (int d = 1; d < 16; d <<= 1) s2 += __shfl_xor(s2, d, 64);
            lgp[r][e] = s2;
        }
    if (lr < 4) {
        const int r = lr;
        const int q = q0 + w * 16 + qd * 4 + r;
        #pragma unroll
        for (int e = 0; e < 8; e++)
            plog[(size_t)(b * S_ + q) * 128 + h * 8 + e] = lgp[r][e] / lsum[r];
    }
}

// ---------------------------------------------------------------------------
// Sum per-head logits, softmax over 8 experts, top-2, build expert lists.
// ---------------------------------------------------------------------------
__global__ void gate_finalize(const float* __restrict__ plog,
    const float* __restrict__ gate_b, const float* __restrict__ c0,
    float* __restrict__ gval, int* __restrict__ list, int* __restrict__ counts)
{
    const int tok = blockIdx.x * 256 + threadIdx.x;
    if (tok >= TOKENS) return;
    float lg[8];
    #pragma unroll
    for (int e = 0; e < 8; e++) lg[e] = gate_b[e] + c0[e];
    for (int h = 0; h < H_; h++) {
        #pragma unroll
        for (int e = 0; e < 8; e++) lg[e] += plog[(size_t)tok * 128 + h * 8 + e];
    }
    float m = lg[0];
    #pragma unroll
    for (int e = 1; e < 8; e++) m = fmaxf(m, lg[e]);
    float ex[8], ssum = 0.f;
    #pragma unroll
    for (int e = 0; e < 8; e++) { ex[e] = __expf(lg[e] - m); ssum += ex[e]; }
    const float inv = 1.f / ssum;
    int i0 = 0;
    #pragma unroll
    for (int e = 1; e < 8; e++) if (lg[e] > lg[i0]) i0 = e;
    int i1 = (i0 == 0) ? 1 : 0;
    #pragma unroll
    for (int e = 0; e < 8; e++) if (e != i0 && lg[e] > lg[i1]) i1 = e;
    const int p0 = atomicAdd(&counts[i0], 1);
    list[i0 * TOKENS + p0] = tok * 2;
    gval[tok * 2] = ex[i0] * inv;
    const int p1 = atomicAdd(&counts[i1], 1);
    list[i1 * TOKENS + p1] = tok * 2 + 1;
    gval[tok * 2 + 1] = ex[i1] * inv;
}

// ---------------------------------------------------------------------------
// Gathered expert GEMM (bf16): sel[ent] = g * (attn[tok] @ ew[e]^T + eb[e])
// ---------------------------------------------------------------------------
__global__ __launch_bounds__(256,2) void gemm_expert(
    const u16* __restrict__ Abf, const u16* __restrict__ ewh,
    const float* __restrict__ eb, const int* __restrict__ list,
    const int* __restrict__ counts, const float* __restrict__ gval,
    u16* __restrict__ sel)
{
    const int e = blockIdx.z;
    const int cnt = counts[e];
    const int m0 = blockIdx.y * 128;
    if (m0 >= cnt) return;
    __shared__ __align__(16) u16 sA[128*32], sB[128*32];
    __shared__ int sEnt[128];
    const int t = threadIdx.x;
    if (t < 128) sEnt[t] = (m0 + t < cnt) ? list[e * TOKENS + m0 + t] : -1;
    __syncthreads();
    const int n0 = blockIdx.x * 128;
    const int lane = t & 63, w = t >> 6;
    const int wm = w >> 1, wn = w & 1;
    const int lr = lane & 15, qd = lane >> 4;
    const int e0 = sEnt[t >> 2], e1 = sEnt[64 + (t >> 2)];
    const u16* ga0 = Abf + (size_t)(e0 < 0 ? 0 : (e0 >> 1)) * E_ + (t & 3) * 8;
    const u16* ga1 = Abf + (size_t)(e1 < 0 ? 0 : (e1 >> 1)) * E_ + (t & 3) * 8;
    const u16* gb0 = ewh + (size_t)e * E_ * E_ + (size_t)(n0 + (t >> 2)) * E_ + (t & 3) * 8;
    const u16* gb1 = gb0 + 64 * E_;
    f32x4 acc[4][4] = {};
    for (int k0 = 0; k0 < E_; k0 += 32) {
        {
            const int l0 = (t & 192) * 16;
            const int l1 = (256 + (t & 192)) * 16;
            gl2lds16(ga0 + k0, (char*)sA + l0);
            gl2lds16(ga1 + k0, (char*)sA + l1);
            gl2lds16(gb0 + k0, (char*)sB + l0);
            gl2lds16(gb1 + k0, (char*)sB + l1);
        }
        __syncthreads();
        bf16x8 af[4], bf[4];
        #pragma unroll
        for (int i = 0; i < 4; i++) {
            af[i] = *(const bf16x8*)&sA[(wm*64 + i*16 + lr)*32 + qd*8];
            bf[i] = *(const bf16x8*)&sB[(wn*64 + i*16 + lr)*32 + qd*8];
        }
        #pragma unroll
        for (int i = 0; i < 4; i++)
            #pragma unroll
            for (int j = 0; j < 4; j++)
                acc[i][j] = MFMA16(af[i], bf[j], acc[i][j]);
        __syncthreads();
    }
    #pragma unroll
    for (int i = 0; i < 4; i++)
        #pragma unroll
        for (int r = 0; r < 4; r++) {
            const int local = wm*64 + i*16 + qd*4 + r;
            const int ent = sEnt[local];
            if (ent < 0) continue;
            const float g = gval[ent];
            #pragma unroll
            for (int j = 0; j < 4; j++) {
                const int col = n0 + wn*64 + j*16 + lr;
                sel[(size_t)ent * E_ + col] = f2bf((acc[i][j][r] + eb[e * E_ + col]) * g);
            }
        }
}

// ---------------------------------------------------------------------------
// moe[tok] = sel[tok*2] + sel[tok*2+1]  (bf16 in/out)
// ---------------------------------------------------------------------------
__global__ void combine_kernel(const u16* __restrict__ sel, u16* __restrict__ moe)
{
    const int g = blockIdx.x * 256 + threadIdx.x;
    const int tok = g >> 8;
    const int c = (g & 255) * 4;
    const u16* a = sel + (size_t)tok * 2048 + c;
    float o[4];
    #pragma unroll
    for (int j = 0; j < 4; j++) o[j] = bf2f(a[j]) + bf2f(a[1024 + j]);
    ushort4 R = {f2bf(o[0]), f2bf(o[1]), f2bf(o[2]), f2bf(o[3])};
    *(ushort4*)(moe + (size_t)tok * E_ + c) = R;
}

// ---------------------------------------------------------------------------
// FFN GEMM (bf16) + bias + fp32 residual -> fp32 out
// ---------------------------------------------------------------------------
__global__ __launch_bounds__(256,2) void gemm_ffn(
    const u16* __restrict__ Ah, const u16* __restrict__ Bh,
    const float* __restrict__ bias, const float* __restrict__ res,
    float* __restrict__ C)
{
    __shared__ __align__(16) u16 sA[128*32], sB[128*32];
    const int t = threadIdx.x;
    const int m0 = blockIdx.y * 128, n0 = blockIdx.x * 128;
    const int lane = t & 63, w = t >> 6;
    const int wm = w >> 1, wn = w & 1;
    const int lr = lane & 15, qd = lane >> 4;
    f32x4 acc[4][4] = {};
    const size_t gA = (size_t)(m0 + (t >> 2)) * E_ + (t & 3) * 8;
    const size_t gB = (size_t)(n0 + (t >> 2)) * E_ + (t & 3) * 8;
    for (int k0 = 0; k0 < E_; k0 += 32) {
        #pragma unroll
        for (int is = 0; is < 2; is++) {
            const int ldo = (is * 256 + (t & 192)) * 16;
            const size_t ro = (size_t)is * 64 * E_;
            gl2lds16(Ah + gA + ro + k0, (char*)sA + ldo);
            gl2lds16(Bh + gB + ro + k0, (char*)sB + ldo);
        }
        __syncthreads();
        bf16x8 af[4], bf[4];
        #pragma unroll
        for (int i = 0; i < 4; i++) {
            af[i] = *(const bf16x8*)&sA[(wm*64 + i*16 + lr)*32 + qd*8];
            bf[i] = *(const bf16x8*)&sB[(wn*64 + i*16 + lr)*32 + qd*8];
        }
        #pragma unroll
        for (int i = 0; i < 4; i++)
            #pragma unroll
            for (int j = 0; j < 4; j++)
                acc[i][j] = MFMA16(af[i], bf[j], acc[i][j]);
        __syncthreads();
    }
    #pragma unroll
    for (int i = 0; i < 4; i++)
        #pragma unroll
        for (int r = 0; r < 4; r++) {
            const int tok = m0 + wm*64 + i*16 + qd*4 + r;
            #pragma unroll
            for (int j = 0; j < 4; j++) {
                const int col = n0 + wn*64 + j*16 + lr;
                C[(size_t)tok * E_ + col] = acc[i][j][r] + bias[col] + res[(size_t)tok * E_ + col];
            }
        }
}

// ---------------------------------------------------------------------------
extern "C" void kernel_launch(void* const* d_in, const int* in_sizes, int n_in,
                              void* d_out, int out_size, void* d_ws, size_t ws_size,
                              hipStream_t stream) {
    const float* x      = (const float*)d_in[0];
    const float* q_w    = (const float*)d_in[1];
    const float* q_b    = (const float*)d_in[2];
    const float* k_w    = (const float*)d_in[3];
    const float* k_b    = (const float*)d_in[4];
    const float* v_w    = (const float*)d_in[5];
    const float* v_b    = (const float*)d_in[6];
    const float* gate_w = (const float*)d_in[7];
    const float* gate_b = (const float*)d_in[8];
    const float* ew     = (const float*)d_in[9];
    const float* eb     = (const float*)d_in[10];
    const float* ffn_w  = (const float*)d_in[11];
    const float* ffn_b  = (const float*)d_in[12];
    float* out = (float*)d_out;

    char* p = (char*)d_ws;
    auto alloc = [&](size_t bytes) { char* r = p; p += (bytes + 255) & ~(size_t)255; return r; };
    u16* xh   = (u16*)alloc((size_t)TOKENS*E_*2);
    u16* xl   = (u16*)alloc((size_t)TOKENS*E_*2);
    u16* qwh  = (u16*)alloc((size_t)E_*E_*2);
    u16* qwl  = (u16*)alloc((size_t)E_*E_*2);
    u16* kwh  = (u16*)alloc((size_t)E_*E_*2);
    u16* kwl  = (u16*)alloc((size_t)E_*E_*2);
    u16* vwh  = (u16*)alloc((size_t)E_*E_*2);
    u16* fwh  = (u16*)alloc((size_t)E_*E_*2);
    u16* ewh  = (u16*)alloc((size_t)NE_*E_*E_*2);
    u16* Qhb  = (u16*)alloc((size_t)TOKENS*E_*2);
    u16* Qlb  = (u16*)alloc((size_t)TOKENS*E_*2);
    u16* Khb  = (u16*)alloc((size_t)TOKENS*E_*2);
    u16* Klb  = (u16*)alloc((size_t)TOKENS*E_*2);
    u16* Vtb  = (u16*)alloc((size_t)TOKENS*E_*2);
    u16* abf  = (u16*)alloc((size_t)TOKENS*E_*2);
    u16* selb = (u16*)alloc((size_t)2*TOKENS*E_*2);
    u16* moeb = (u16*)alloc((size_t)TOKENS*E_*2);
    float* Mf  = (float*)alloc((size_t)128*E_*4);
    float* vgb = (float*)alloc((size_t)TOKENS*128*4);
    float* plg = (float*)alloc((size_t)TOKENS*128*4);
    float* c0  = (float*)alloc(256);
    float* gvl = (float*)alloc((size_t)2*TOKENS*4);
    int*   lst = (int*)alloc((size_t)NE_*TOKENS*4);
    int*   cnt = (int*)alloc(256);

    hipMemsetAsync(cnt, 0, 256, stream);
    hipMemsetAsync(c0, 0, 256, stream);

    cvt_split_k<<<4096, 256, 0, stream>>>(x, xh, xl, TOKENS*E_/4);
    cvt_split_k<<<1024, 256, 0, stream>>>(q_w, qwh, qwl, E_*E_/4);
    cvt_split_k<<<1024, 256, 0, stream>>>(k_w, kwh, kwl, E_*E_/4);
    cvt_plain_k<<<1024, 256, 0, stream>>>(v_w, vwh, E_*E_/4);
    cvt_plain_k<<<1024, 256, 0, stream>>>(ffn_w, fwh, E_*E_/4);
    cvt_plain_k<<<8192, 256, 0, stream>>>(ew, ewh, NE_*E_*E_/4);
    gwvw_kernel<<<dim3(4,16), 256, 0, stream>>>(gate_w, v_w, v_b, Mf, c0);
    gemm_nt_kernel<<<dim3(2,64), 256, 0, stream>>>(x, Mf, nullptr, nullptr, vgb, TOKENS, 128, E_);
    gemm_qk_rope<<<dim3(8,32), 256, 0, stream>>>(xh, xl, qwh, qwl, q_b, Qhb, Qlb);
    gemm_qk_rope<<<dim3(8,32), 256, 0, stream>>>(xh, xl, kwh, kwl, k_b, Khb, Klb);
    gemm_v<<<dim3(8,32), 256, 0, stream>>>(xh, vwh, v_b, Vtb);
    attn_kernel<<<dim3(32,16,2), 256, 0, stream>>>(Qhb, Qlb, Khb, Klb, Vtb, vgb, abf, plg);
    gate_finalize<<<16, 256, 0, stream>>>(plg, gate_b, c0, gvl, lst, cnt);
    gemm_expert<<<dim3(8,32,8), 256, 0, stream>>>(abf, ewh, eb, lst, cnt, gvl, selb);
    combine_kernel<<<4096, 256, 0, stream>>>(selb, moeb);
    gemm_ffn<<<dim3(8,32), 256, 0, stream>>>(moeb, fwh, ffn_b, x, out);
}

// Round 3
// 452.128 us; speedup vs baseline: 4.1897x; 1.5463x over previous
//
#include <hip/hip_runtime.h>
#include <hip/hip_bf16.h>

#define B_ 2
#define S_ 2048
#define E_ 1024
#define H_ 16
#define D_ 64
#define NE_ 8
#define TOKENS (B_*S_)   // 4096

typedef __attribute__((ext_vector_type(8))) short bf16x8;
typedef __attribute__((ext_vector_type(4))) float f32x4;
typedef unsigned short u16;
typedef unsigned int u32;

__device__ __forceinline__ u16 f2bf(float f) {
    u32 u = __float_as_uint(f);
    u32 r = u + 0x7fffu + ((u >> 16) & 1u);
    return (u16)(r >> 16);
}
__device__ __forceinline__ float bf2f(u16 h) {
    return __uint_as_float(((u32)h) << 16);
}
__device__ __forceinline__ void gl2lds16(const void* g, void* l) {
    __builtin_amdgcn_global_load_lds(
        (__attribute__((address_space(1))) void*)(g),
        (__attribute__((address_space(3))) void*)(l), 16, 0, 0);
}
#define MFMA16(a,b,c) __builtin_amdgcn_mfma_f32_16x16x32_bf16(a,b,c,0,0,0)

// ---------------------------------------------------------------------------
// fp32 -> bf16 conversion
// ---------------------------------------------------------------------------
__global__ void cvt_plain_k(const float* __restrict__ s, u16* __restrict__ h, int n4)
{
    const int i = blockIdx.x * 256 + threadIdx.x;
    if (i >= n4) return;
    const float4 v = *(const float4*)(s + (size_t)i * 4);
    ushort4 H = {f2bf(v.x), f2bf(v.y), f2bf(v.z), f2bf(v.w)};
    *(ushort4*)(h + (size_t)i * 4) = H;
}

// ---------------------------------------------------------------------------
// bf16 MFMA GEMM (Q/K projections) + fused RoPE epilogue.
// Output bf16 head-major [b][h][s][d]. 128x128 tile, BK=32, 4 waves.
// ---------------------------------------------------------------------------
__global__ __launch_bounds__(256,2) void gemm_qk_rope(
    const u16* __restrict__ Ah, const u16* __restrict__ Bh,
    const float* __restrict__ bias, u16* __restrict__ Oh)
{
    __shared__ __align__(16) u16 sA[128*32], sB[128*32];
    const int t = threadIdx.x;
    const int m0 = blockIdx.y * 128, n0 = blockIdx.x * 128;
    const int lane = t & 63, w = t >> 6;
    const int wm = w >> 1, wn = w & 1;
    const int lr = lane & 15, qd = lane >> 4;
    f32x4 acc[4][4] = {};
    const size_t gA = (size_t)(m0 + (t >> 2)) * E_ + (t & 3) * 8;
    const size_t gB = (size_t)(n0 + (t >> 2)) * E_ + (t & 3) * 8;
    for (int k0 = 0; k0 < E_; k0 += 32) {
        #pragma unroll
        for (int is = 0; is < 2; is++) {
            const int ldo = (is * 256 + (t & 192)) * 16;
            const size_t ro = (size_t)is * 64 * E_;
            gl2lds16(Ah + gA + ro + k0, (char*)sA + ldo);
            gl2lds16(Bh + gB + ro + k0, (char*)sB + ldo);
        }
        __syncthreads();
        bf16x8 af[4], bfr[4];
        #pragma unroll
        for (int i = 0; i < 4; i++) {
            af[i]  = *(const bf16x8*)&sA[(wm*64 + i*16 + lr)*32 + qd*8];
            bfr[i] = *(const bf16x8*)&sB[(wn*64 + i*16 + lr)*32 + qd*8];
        }
        #pragma unroll
        for (int i = 0; i < 4; i++)
            #pragma unroll
            for (int j = 0; j < 4; j++)
                acc[i][j] = MFMA16(af[i], bfr[j], acc[i][j]);
        __syncthreads();
    }
    // Epilogue: bias + RoPE + head-major bf16 store.
    // Wave's 64 columns == one head; pair (d, d+32) is (subtile j, j+2), same lane.
    const int head = (n0 + wn * 64) >> 6;
    const float C32 = 0.41524101186091903f;   // log2(10000)/32
    #pragma unroll
    for (int j = 0; j < 2; j++) {
        const int d1 = j * 16 + lr;
        const float b1 = bias[head * 64 + d1];
        const float b2 = bias[head * 64 + d1 + 32];
        const float inv = exp2f(-(float)d1 * C32);
        #pragma unroll
        for (int i = 0; i < 4; i++) {
            #pragma unroll
            for (int r = 0; r < 4; r++) {
                const int tok = m0 + wm*64 + i*16 + qd*4 + r;
                const int bb = tok >> 11, ss = tok & (S_ - 1);
                float sn, cs;
                sincosf((float)ss * inv, &sn, &cs);
                const float q1 = acc[i][j][r]   + b1;
                const float q2 = acc[i][j+2][r] + b2;
                const size_t o = (((size_t)bb * H_ + head) * S_ + ss) * 64 + d1;
                Oh[o]    = f2bf(q1 * cs - q2 * sn);
                Oh[o+32] = f2bf(q2 * cs + q1 * sn);
            }
        }
    }
}

// ---------------------------------------------------------------------------
// bf16 GEMM for V projection; epilogue writes transposed bf16 Vt[b][h][d][s].
// ---------------------------------------------------------------------------
__global__ __launch_bounds__(256,2) void gemm_v(
    const u16* __restrict__ Ah, const u16* __restrict__ Bh,
    const float* __restrict__ bias, u16* __restrict__ Vt)
{
    __shared__ __align__(16) u16 sA[128*32], sB[128*32];
    const int t = threadIdx.x;
    const int m0 = blockIdx.y * 128, n0 = blockIdx.x * 128;
    const int lane = t & 63, w = t >> 6;
    const int wm = w >> 1, wn = w & 1;
    const int lr = lane & 15, qd = lane >> 4;
    f32x4 acc[4][4] = {};
    const size_t gA = (size_t)(m0 + (t >> 2)) * E_ + (t & 3) * 8;
    const size_t gB = (size_t)(n0 + (t >> 2)) * E_ + (t & 3) * 8;
    for (int k0 = 0; k0 < E_; k0 += 32) {
        #pragma unroll
        for (int is = 0; is < 2; is++) {
            const int ldo = (is * 256 + (t & 192)) * 16;
            const size_t ro = (size_t)is * 64 * E_;
            gl2lds16(Ah + gA + ro + k0, (char*)sA + ldo);
            gl2lds16(Bh + gB + ro + k0, (char*)sB + ldo);
        }
        __syncthreads();
        bf16x8 af[4], bfr[4];
        #pragma unroll
        for (int i = 0; i < 4; i++) {
            af[i]  = *(const bf16x8*)&sA[(wm*64 + i*16 + lr)*32 + qd*8];
            bfr[i] = *(const bf16x8*)&sB[(wn*64 + i*16 + lr)*32 + qd*8];
        }
        #pragma unroll
        for (int i = 0; i < 4; i++)
            #pragma unroll
            for (int j = 0; j < 4; j++)
                acc[i][j] = MFMA16(af[i], bfr[j], acc[i][j]);
        __syncthreads();
    }
    const int head = (n0 + wn * 64) >> 6;
    #pragma unroll
    for (int j = 0; j < 4; j++) {
        const int d = j * 16 + lr;
        const float bv = bias[head * 64 + d];
        #pragma unroll
        for (int i = 0; i < 4; i++)
            #pragma unroll
            for (int r = 0; r < 4; r++) {
                const int tok = m0 + wm*64 + i*16 + qd*4 + r;
                const int bb = tok >> 11, ss = tok & (S_ - 1);
                Vt[(((size_t)bb * H_ + head) * 64 + d) * S_ + ss] = f2bf(acc[i][j][r] + bv);
            }
    }
}

// ---------------------------------------------------------------------------
// Flash attention, bf16 MFMA, fragment-major LDS (conflict-free reads).
// Block = (b, h, 128 queries), 4 waves; each wave 2 strips of 16 q-rows.
// No-max softmax (scores bounded); lane-local lsum reduced once at end.
// Writes attn_out bf16 (expert A operand) and fp32 (gate path).
// ---------------------------------------------------------------------------
__global__ __launch_bounds__(256,2) void attn_kernel(
    const u16* __restrict__ Q, const u16* __restrict__ K,
    const u16* __restrict__ Vt,
    u16* __restrict__ attn_bf, float* __restrict__ attn_f32)
{
    __shared__ __align__(16) u16 sK[64*64];        // frag-major: CH=(sb*8+hh*4+qd), piece=lr
    __shared__ __align__(16) u16 sV[64*64];        // frag-major over (d-group, s-half, s-chunk)
    __shared__ __align__(16) u16 sP[4][2][16*40];  // per-wave, per-strip, stride 40 u16
    const int t = threadIdx.x, lane = t & 63, w = t >> 6;
    const int lr = lane & 15, qd = lane >> 4;
    const int q0 = blockIdx.x * 128;
    const int h = blockIdx.y, b = blockIdx.z;
    const size_t bhS = ((size_t)b * H_ + h) * S_;
    const size_t bhD = ((size_t)b * H_ + h) * 64;
    // Q fragments: strip p covers q rows [q0 + p*64 + w*16, +16)
    bf16x8 qf[2][2];
    #pragma unroll
    for (int p = 0; p < 2; p++) {
        const size_t qa = (bhS + q0 + p*64 + w*16 + lr) * 64 + qd * 8;
        qf[p][0] = *(const bf16x8*)&Q[qa];
        qf[p][1] = *(const bf16x8*)&Q[qa + 32];
    }
    f32x4 O[2][4] = {};
    float lsum[2][4] = {};
    for (int j0 = 0; j0 < S_; j0 += 64) {
        // stage K and V tiles, frag-major, via per-lane global_load_lds
        #pragma unroll
        for (int it = 0; it < 2; it++) {
            const int CH = (it*4 + w)*4 + qd;
            const int sbs = CH >> 3;
            const int doff = ((CH >> 2) & 1)*32 + (CH & 3)*8;
            gl2lds16(&K [(bhS + j0 + sbs*16 + lr)*64 + doff],
                     (char*)sK + (it*4 + w)*1024);
            gl2lds16(&Vt[(bhD + sbs*16 + lr)*S_ + j0 + doff],
                     (char*)sV + (it*4 + w)*1024);
        }
        __syncthreads();
        // S = Q K^T for both strips (K frags shared)
        f32x4 Sv[2][4];
        #pragma unroll
        for (int sb = 0; sb < 4; sb++) {
            bf16x8 k0 = *(const bf16x8*)&sK[(sb*8 + qd)*128 + lr*8];
            bf16x8 k1 = *(const bf16x8*)&sK[(sb*8 + 4 + qd)*128 + lr*8];
            f32x4 a0 = {}, a1 = {};
            a0 = MFMA16(qf[0][0], k0, a0);
            a0 = MFMA16(qf[0][1], k1, a0);
            a1 = MFMA16(qf[1][0], k0, a1);
            a1 = MFMA16(qf[1][1], k1, a1);
            Sv[0][sb] = a0;
            Sv[1][sb] = a1;
        }
        // no-max softmax: p = exp(s/8); lane-local partial sums
        #pragma unroll
        for (int p = 0; p < 2; p++) {
            float ps[4] = {};
            #pragma unroll
            for (int sb = 0; sb < 4; sb++)
                #pragma unroll
                for (int r = 0; r < 4; r++) {
                    const float pv = __expf(Sv[p][sb][r] * 0.125f);
                    ps[r] += pv;
                    sP[w][p][(qd*4 + r)*40 + sb*16 + lr] = f2bf(pv);
                }
            #pragma unroll
            for (int r = 0; r < 4; r++) lsum[p][r] += ps[r];
        }
        // PV (P round-trips LDS: C-layout -> A-layout)
        #pragma unroll
        for (int p = 0; p < 2; p++) {
            bf16x8 p0 = *(const bf16x8*)&sP[w][p][lr*40 + qd*8];
            bf16x8 p1 = *(const bf16x8*)&sP[w][p][lr*40 + 32 + qd*8];
            #pragma unroll
            for (int ds = 0; ds < 4; ds++) {
                bf16x8 v0 = *(const bf16x8*)&sV[(ds*8 + qd)*128 + lr*8];
                bf16x8 v1 = *(const bf16x8*)&sV[(ds*8 + 4 + qd)*128 + lr*8];
                O[p][ds] = MFMA16(p0, v0, O[p][ds]);
                O[p][ds] = MFMA16(p1, v1, O[p][ds]);
            }
        }
        __syncthreads();
    }
    // reduce lsum across the 16 lr lanes (bits 0..3)
    float linv[2][4];
    #pragma unroll
    for (int p = 0; p < 2; p++)
        #pragma unroll
        for (int r = 0; r < 4; r++) {
            float s2 = lsum[p][r];
            s2 += __shfl_xor(s2, 1, 64);
            s2 += __shfl_xor(s2, 2, 64);
            s2 += __shfl_xor(s2, 4, 64);
            s2 += __shfl_xor(s2, 8, 64);
            linv[p][r] = 1.f / s2;
        }
    #pragma unroll
    for (int p = 0; p < 2; p++)
        #pragma unroll
        for (int ds = 0; ds < 4; ds++)
            #pragma unroll
            for (int r = 0; r < 4; r++) {
                const int q = q0 + p*64 + w*16 + qd*4 + r;
                const size_t o = (size_t)(b*S_ + q)*E_ + h*64 + ds*16 + lr;
                const float val = O[p][ds][r] * linv[p][r];
                attn_bf[o]  = f2bf(val);
                attn_f32[o] = val;
            }
}

// ---------------------------------------------------------------------------
// Gate logits (fp32) -> softmax -> top2 -> expert token lists.
// One wave per token (4 tokens per block).
// ---------------------------------------------------------------------------
__global__ __launch_bounds__(256) void gate_topk_kernel(
    const float* __restrict__ attn_f32, const float* __restrict__ gate_w,
    const float* __restrict__ gate_b, float* __restrict__ gval,
    int* __restrict__ list, int* __restrict__ counts)
{
    const int t = threadIdx.x;
    const int token = blockIdx.x * 4 + (t >> 6);
    const int lane  = t & 63;
    const float* a = attn_f32 + (size_t)token * E_;
    float part[NE_] = {};
    for (int i = lane; i < E_; i += 64) {
        const float av = a[i];
        #pragma unroll
        for (int n = 0; n < NE_; n++) part[n] += av * gate_w[n*E_ + i];
    }
    #pragma unroll
    for (int n = 0; n < NE_; n++) {
        #pragma unroll
        for (int off = 32; off >= 1; off >>= 1)
            part[n] += __shfl_down(part[n], off, 64);
    }
    if (lane == 0) {
        float lg[NE_];
        #pragma unroll
        for (int n = 0; n < NE_; n++) lg[n] = part[n] + gate_b[n];
        float m = lg[0];
        #pragma unroll
        for (int n = 1; n < NE_; n++) m = fmaxf(m, lg[n]);
        float ex[NE_], ssum = 0.f;
        #pragma unroll
        for (int n = 0; n < NE_; n++) { ex[n] = __expf(lg[n]-m); ssum += ex[n]; }
        const float invs = 1.f / ssum;
        int i0 = 0;
        #pragma unroll
        for (int n = 1; n < NE_; n++) if (lg[n] > lg[i0]) i0 = n;
        int i1 = (i0 == 0) ? 1 : 0;
        #pragma unroll
        for (int n = 0; n < NE_; n++) if (n != i0 && lg[n] > lg[i1]) i1 = n;
        const int pos0 = atomicAdd(&counts[i0], 1);
        list[i0*TOKENS + pos0] = token*2;
        gval[token*2] = ex[i0]*invs;
        const int pos1 = atomicAdd(&counts[i1], 1);
        list[i1*TOKENS + pos1] = token*2 + 1;
        gval[token*2+1] = ex[i1]*invs;
    }
}

// ---------------------------------------------------------------------------
// Gathered expert GEMM (bf16): sel[ent] = g * (attn[tok] @ ew[e]^T + eb[e])
// ---------------------------------------------------------------------------
__global__ __launch_bounds__(256,2) void gemm_expert(
    const u16* __restrict__ Abf, const u16* __restrict__ ewh,
    const float* __restrict__ eb, const int* __restrict__ list,
    const int* __restrict__ counts, const float* __restrict__ gval,
    u16* __restrict__ sel)
{
    const int e = blockIdx.z;
    const int cnt = counts[e];
    const int m0 = blockIdx.y * 128;
    if (m0 >= cnt) return;
    __shared__ __align__(16) u16 sA[128*32], sB[128*32];
    __shared__ int sEnt[128];
    const int t = threadIdx.x;
    if (t < 128) sEnt[t] = (m0 + t < cnt) ? list[e * TOKENS + m0 + t] : -1;
    __syncthreads();
    const int n0 = blockIdx.x * 128;
    const int lane = t & 63, w = t >> 6;
    const int wm = w >> 1, wn = w & 1;
    const int lr = lane & 15, qd = lane >> 4;
    const int e0 = sEnt[t >> 2], e1 = sEnt[64 + (t >> 2)];
    const u16* ga0 = Abf + (size_t)(e0 < 0 ? 0 : (e0 >> 1)) * E_ + (t & 3) * 8;
    const u16* ga1 = Abf + (size_t)(e1 < 0 ? 0 : (e1 >> 1)) * E_ + (t & 3) * 8;
    const u16* gb0 = ewh + (size_t)e * E_ * E_ + (size_t)(n0 + (t >> 2)) * E_ + (t & 3) * 8;
    const u16* gb1 = gb0 + 64 * E_;
    f32x4 acc[4][4] = {};
    for (int k0 = 0; k0 < E_; k0 += 32) {
        {
            const int l0 = (t & 192) * 16;
            const int l1 = (256 + (t & 192)) * 16;
            gl2lds16(ga0 + k0, (char*)sA + l0);
            gl2lds16(ga1 + k0, (char*)sA + l1);
            gl2lds16(gb0 + k0, (char*)sB + l0);
            gl2lds16(gb1 + k0, (char*)sB + l1);
        }
        __syncthreads();
        bf16x8 af[4], bfr[4];
        #pragma unroll
        for (int i = 0; i < 4; i++) {
            af[i]  = *(const bf16x8*)&sA[(wm*64 + i*16 + lr)*32 + qd*8];
            bfr[i] = *(const bf16x8*)&sB[(wn*64 + i*16 + lr)*32 + qd*8];
        }
        #pragma unroll
        for (int i = 0; i < 4; i++)
            #pragma unroll
            for (int j = 0; j < 4; j++)
                acc[i][j] = MFMA16(af[i], bfr[j], acc[i][j]);
        __syncthreads();
    }
    #pragma unroll
    for (int i = 0; i < 4; i++)
        #pragma unroll
        for (int r = 0; r < 4; r++) {
            const int local = wm*64 + i*16 + qd*4 + r;
            const int ent = sEnt[local];
            if (ent < 0) continue;
            const float g = gval[ent];
            #pragma unroll
            for (int j = 0; j < 4; j++) {
                const int col = n0 + wn*64 + j*16 + lr;
                sel[(size_t)ent * E_ + col] = f2bf((acc[i][j][r] + eb[e * E_ + col]) * g);
            }
        }
}

// ---------------------------------------------------------------------------
// moe[tok] = sel[tok*2] + sel[tok*2+1]  (bf16 in/out)
// ---------------------------------------------------------------------------
__global__ void combine_kernel(const u16* __restrict__ sel, u16* __restrict__ moe)
{
    const int g = blockIdx.x * 256 + threadIdx.x;
    const int tok = g >> 8;
    const int c = (g & 255) * 4;
    const u16* a = sel + (size_t)tok * 2048 + c;
    float o[4];
    #pragma unroll
    for (int j = 0; j < 4; j++) o[j] = bf2f(a[j]) + bf2f(a[1024 + j]);
    ushort4 R = {f2bf(o[0]), f2bf(o[1]), f2bf(o[2]), f2bf(o[3])};
    *(ushort4*)(moe + (size_t)tok * E_ + c) = R;
}

// ---------------------------------------------------------------------------
// FFN GEMM (bf16) + bias + fp32 residual -> fp32 out
// ---------------------------------------------------------------------------
__global__ __launch_bounds__(256,2) void gemm_ffn(
    const u16* __restrict__ Ah, const u16* __restrict__ Bh,
    const float* __restrict__ bias, const float* __restrict__ res,
    float* __restrict__ C)
{
    __shared__ __align__(16) u16 sA[128*32], sB[128*32];
    const int t = threadIdx.x;
    const int m0 = blockIdx.y * 128, n0 = blockIdx.x * 128;
    const int lane = t & 63, w = t >> 6;
    const int wm = w >> 1, wn = w & 1;
    const int lr = lane & 15, qd = lane >> 4;
    f32x4 acc[4][4] = {};
    const size_t gA = (size_t)(m0 + (t >> 2)) * E_ + (t & 3) * 8;
    const size_t gB = (size_t)(n0 + (t >> 2)) * E_ + (t & 3) * 8;
    for (int k0 = 0; k0 < E_; k0 += 32) {
        #pragma unroll
        for (int is = 0; is < 2; is++) {
            const int ldo = (is * 256 + (t & 192)) * 16;
            const size_t ro = (size_t)is * 64 * E_;
            gl2lds16(Ah + gA + ro + k0, (char*)sA + ldo);
            gl2lds16(Bh + gB + ro + k0, (char*)sB + ldo);
        }
        __syncthreads();
        bf16x8 af[4], bfr[4];
        #pragma unroll
        for (int i = 0; i < 4; i++) {
            af[i]  = *(const bf16x8*)&sA[(wm*64 + i*16 + lr)*32 + qd*8];
            bfr[i] = *(const bf16x8*)&sB[(wn*64 + i*16 + lr)*32 + qd*8];
        }
        #pragma unroll
        for (int i = 0; i < 4; i++)
            #pragma unroll
            for (int j = 0; j < 4; j++)
                acc[i][j] = MFMA16(af[i], bfr[j], acc[i][j]);
        __syncthreads();
    }
    #pragma unroll
    for (int i = 0; i < 4; i++)
        #pragma unroll
        for (int r = 0; r < 4; r++) {
            const int tok = m0 + wm*64 + i*16 + qd*4 + r;
            #pragma unroll
            for (int j = 0; j < 4; j++) {
                const int col = n0 + wn*64 + j*16 + lr;
                C[(size_t)tok * E_ + col] = acc[i][j][r] + bias[col] + res[(size_t)tok * E_ + col];
            }
        }
}

// ---------------------------------------------------------------------------
extern "C" void kernel_launch(void* const* d_in, const int* in_sizes, int n_in,
                              void* d_out, int out_size, void* d_ws, size_t ws_size,
                              hipStream_t stream) {
    const float* x      = (const float*)d_in[0];
    const float* q_w    = (const float*)d_in[1];
    const float* q_b    = (const float*)d_in[2];
    const float* k_w    = (const float*)d_in[3];
    const float* k_b    = (const float*)d_in[4];
    const float* v_w    = (const float*)d_in[5];
    const float* v_b    = (const float*)d_in[6];
    const float* gate_w = (const float*)d_in[7];
    const float* gate_b = (const float*)d_in[8];
    const float* ew     = (const float*)d_in[9];
    const float* eb     = (const float*)d_in[10];
    const float* ffn_w  = (const float*)d_in[11];
    const float* ffn_b  = (const float*)d_in[12];
    float* out = (float*)d_out;

    char* p = (char*)d_ws;
    auto alloc = [&](size_t bytes) { char* r = p; p += (bytes + 255) & ~(size_t)255; return r; };
    u16* xh   = (u16*)alloc((size_t)TOKENS*E_*2);
    u16* qwh  = (u16*)alloc((size_t)E_*E_*2);
    u16* kwh  = (u16*)alloc((size_t)E_*E_*2);
    u16* vwh  = (u16*)alloc((size_t)E_*E_*2);
    u16* fwh  = (u16*)alloc((size_t)E_*E_*2);
    u16* ewh  = (u16*)alloc((size_t)NE_*E_*E_*2);
    u16* Qhb  = (u16*)alloc((size_t)TOKENS*E_*2);
    u16* Khb  = (u16*)alloc((size_t)TOKENS*E_*2);
    u16* Vtb  = (u16*)alloc((size_t)TOKENS*E_*2);
    u16* abf  = (u16*)alloc((size_t)TOKENS*E_*2);
    float* af32 = (float*)alloc((size_t)TOKENS*E_*4);
    u16* selb = (u16*)alloc((size_t)2*TOKENS*E_*2);
    u16* moeb = (u16*)alloc((size_t)TOKENS*E_*2);
    float* gvl = (float*)alloc((size_t)2*TOKENS*4);
    int*   lst = (int*)alloc((size_t)NE_*TOKENS*4);
    int*   cnt = (int*)alloc(256);

    hipMemsetAsync(cnt, 0, 256, stream);

    cvt_plain_k<<<4096, 256, 0, stream>>>(x, xh, TOKENS*E_/4);
    cvt_plain_k<<<1024, 256, 0, stream>>>(q_w, qwh, E_*E_/4);
    cvt_plain_k<<<1024, 256, 0, stream>>>(k_w, kwh, E_*E_/4);
    cvt_plain_k<<<1024, 256, 0, stream>>>(v_w, vwh, E_*E_/4);
    cvt_plain_k<<<1024, 256, 0, stream>>>(ffn_w, fwh, E_*E_/4);
    cvt_plain_k<<<8192, 256, 0, stream>>>(ew, ewh, NE_*E_*E_/4);

    gemm_qk_rope<<<dim3(8,32), 256, 0, stream>>>(xh, qwh, q_b, Qhb);
    gemm_qk_rope<<<dim3(8,32), 256, 0, stream>>>(xh, kwh, k_b, Khb);
    gemm_v<<<dim3(8,32), 256, 0, stream>>>(xh, vwh, v_b, Vtb);

    attn_kernel<<<dim3(16,16,2), 256, 0, stream>>>(Qhb, Khb, Vtb, abf, af32);

    gate_topk_kernel<<<TOKENS/4, 256, 0, stream>>>(af32, gate_w, gate_b, gvl, lst, cnt);
    gemm_expert<<<dim3(8,32,8), 256, 0, stream>>>(abf, ewh, eb, lst, cnt, gvl, selb);
    combine_kernel<<<4096, 256, 0, stream>>>(selb, moeb);
    gemm_ffn<<<dim3(8,32), 256, 0, stream>>>(moeb, fwh, ffn_b, x, out);
}

// Round 4
// 366.180 us; speedup vs baseline: 5.1731x; 1.2347x over previous
//
#include <hip/hip_runtime.h>
#include <hip/hip_bf16.h>

#define B_ 2
#define S_ 2048
#define E_ 1024
#define H_ 16
#define D_ 64
#define NE_ 8
#define TOKENS (B_*S_)   // 4096

typedef __attribute__((ext_vector_type(8))) short bf16x8;
typedef __attribute__((ext_vector_type(4))) float f32x4;
typedef unsigned short u16;
typedef unsigned int u32;

__device__ __forceinline__ u16 f2bf(float f) {
    u32 u = __float_as_uint(f);
    u32 r = u + 0x7fffu + ((u >> 16) & 1u);
    return (u16)(r >> 16);
}
__device__ __forceinline__ float bf2f(u16 h) {
    return __uint_as_float(((u32)h) << 16);
}
__device__ __forceinline__ void gl2lds16(const void* g, void* l) {
    __builtin_amdgcn_global_load_lds(
        (__attribute__((address_space(1))) void*)(g),
        (__attribute__((address_space(3))) void*)(l), 16, 0, 0);
}
#define MFMA16(a,b,c) __builtin_amdgcn_mfma_f32_16x16x32_bf16(a,b,c,0,0,0)

// ---------------------------------------------------------------------------
// fp32 -> bf16 conversion
// ---------------------------------------------------------------------------
__global__ void cvt_plain_k(const float* __restrict__ s, u16* __restrict__ h, int n4)
{
    const int i = blockIdx.x * 256 + threadIdx.x;
    if (i >= n4) return;
    const float4 v = *(const float4*)(s + (size_t)i * 4);
    ushort4 H = {f2bf(v.x), f2bf(v.y), f2bf(v.z), f2bf(v.w)};
    *(ushort4*)(h + (size_t)i * 4) = H;
}

// ---------------------------------------------------------------------------
// bf16 MFMA GEMM (Q/K projections) + fused RoPE epilogue.
// Output bf16 head-major [b][h][s][d]. 128x128 tile, BK=32, 4 waves.
// ---------------------------------------------------------------------------
__global__ __launch_bounds__(256,2) void gemm_qk_rope(
    const u16* __restrict__ Ah, const u16* __restrict__ Bh,
    const float* __restrict__ bias, u16* __restrict__ Oh)
{
    __shared__ __align__(16) u16 sA[128*32], sB[128*32];
    const int t = threadIdx.x;
    const int m0 = blockIdx.y * 128, n0 = blockIdx.x * 128;
    const int lane = t & 63, w = t >> 6;
    const int wm = w >> 1, wn = w & 1;
    const int lr = lane & 15, qd = lane >> 4;
    f32x4 acc[4][4] = {};
    const size_t gA = (size_t)(m0 + (t >> 2)) * E_ + (t & 3) * 8;
    const size_t gB = (size_t)(n0 + (t >> 2)) * E_ + (t & 3) * 8;
    for (int k0 = 0; k0 < E_; k0 += 32) {
        #pragma unroll
        for (int is = 0; is < 2; is++) {
            const int ldo = (is * 256 + (t & 192)) * 16;
            const size_t ro = (size_t)is * 64 * E_;
            gl2lds16(Ah + gA + ro + k0, (char*)sA + ldo);
            gl2lds16(Bh + gB + ro + k0, (char*)sB + ldo);
        }
        __syncthreads();
        bf16x8 af[4], bfr[4];
        #pragma unroll
        for (int i = 0; i < 4; i++) {
            af[i]  = *(const bf16x8*)&sA[(wm*64 + i*16 + lr)*32 + qd*8];
            bfr[i] = *(const bf16x8*)&sB[(wn*64 + i*16 + lr)*32 + qd*8];
        }
        #pragma unroll
        for (int i = 0; i < 4; i++)
            #pragma unroll
            for (int j = 0; j < 4; j++)
                acc[i][j] = MFMA16(af[i], bfr[j], acc[i][j]);
        __syncthreads();
    }
    // Epilogue: bias + RoPE + head-major bf16 store.
    // Wave's 64 columns == one head; pair (d, d+32) is (subtile j, j+2), same lane.
    const int head = (n0 + wn * 64) >> 6;
    const float C32 = 0.41524101186091903f;   // log2(10000)/32
    #pragma unroll
    for (int j = 0; j < 2; j++) {
        const int d1 = j * 16 + lr;
        const float b1 = bias[head * 64 + d1];
        const float b2 = bias[head * 64 + d1 + 32];
        const float inv = exp2f(-(float)d1 * C32);
        #pragma unroll
        for (int i = 0; i < 4; i++) {
            #pragma unroll
            for (int r = 0; r < 4; r++) {
                const int tok = m0 + wm*64 + i*16 + qd*4 + r;
                const int bb = tok >> 11, ss = tok & (S_ - 1);
                float sn, cs;
                sincosf((float)ss * inv, &sn, &cs);
                const float q1 = acc[i][j][r]   + b1;
                const float q2 = acc[i][j+2][r] + b2;
                const size_t o = (((size_t)bb * H_ + head) * S_ + ss) * 64 + d1;
                Oh[o]    = f2bf(q1 * cs - q2 * sn);
                Oh[o+32] = f2bf(q2 * cs + q1 * sn);
            }
        }
    }
}

// ---------------------------------------------------------------------------
// bf16 GEMM for V projection; epilogue writes transposed bf16 Vt[b][h][d][s].
// ---------------------------------------------------------------------------
__global__ __launch_bounds__(256,2) void gemm_v(
    const u16* __restrict__ Ah, const u16* __restrict__ Bh,
    const float* __restrict__ bias, u16* __restrict__ Vt)
{
    __shared__ __align__(16) u16 sA[128*32], sB[128*32];
    const int t = threadIdx.x;
    const int m0 = blockIdx.y * 128, n0 = blockIdx.x * 128;
    const int lane = t & 63, w = t >> 6;
    const int wm = w >> 1, wn = w & 1;
    const int lr = lane & 15, qd = lane >> 4;
    f32x4 acc[4][4] = {};
    const size_t gA = (size_t)(m0 + (t >> 2)) * E_ + (t & 3) * 8;
    const size_t gB = (size_t)(n0 + (t >> 2)) * E_ + (t & 3) * 8;
    for (int k0 = 0; k0 < E_; k0 += 32) {
        #pragma unroll
        for (int is = 0; is < 2; is++) {
            const int ldo = (is * 256 + (t & 192)) * 16;
            const size_t ro = (size_t)is * 64 * E_;
            gl2lds16(Ah + gA + ro + k0, (char*)sA + ldo);
            gl2lds16(Bh + gB + ro + k0, (char*)sB + ldo);
        }
        __syncthreads();
        bf16x8 af[4], bfr[4];
        #pragma unroll
        for (int i = 0; i < 4; i++) {
            af[i]  = *(const bf16x8*)&sA[(wm*64 + i*16 + lr)*32 + qd*8];
            bfr[i] = *(const bf16x8*)&sB[(wn*64 + i*16 + lr)*32 + qd*8];
        }
        #pragma unroll
        for (int i = 0; i < 4; i++)
            #pragma unroll
            for (int j = 0; j < 4; j++)
                acc[i][j] = MFMA16(af[i], bfr[j], acc[i][j]);
        __syncthreads();
    }
    const int head = (n0 + wn * 64) >> 6;
    #pragma unroll
    for (int j = 0; j < 4; j++) {
        const int d = j * 16 + lr;
        const float bv = bias[head * 64 + d];
        #pragma unroll
        for (int i = 0; i < 4; i++)
            #pragma unroll
            for (int r = 0; r < 4; r++) {
                const int tok = m0 + wm*64 + i*16 + qd*4 + r;
                const int bb = tok >> 11, ss = tok & (S_ - 1);
                Vt[(((size_t)bb * H_ + head) * 64 + d) * S_ + ss] = f2bf(acc[i][j][r] + bv);
            }
    }
}

// ---------------------------------------------------------------------------
// Flash attention, bf16 MFMA, fragment-major LDS (conflict-free reads).
// Block = (b, h, 128 queries), 4 waves; each wave 2 strips of 16 q-rows.
// No-max softmax (scores bounded); lane-local lsum reduced once at end.
// Writes attn_out bf16 (expert A operand) and fp32 (gate path).
// ---------------------------------------------------------------------------
__global__ __launch_bounds__(256,2) void attn_kernel(
    const u16* __restrict__ Q, const u16* __restrict__ K,
    const u16* __restrict__ Vt,
    u16* __restrict__ attn_bf, float* __restrict__ attn_f32)
{
    __shared__ __align__(16) u16 sK[64*64];        // frag-major: CH=(sb*8+hh*4+qd), piece=lr
    __shared__ __align__(16) u16 sV[64*64];        // frag-major over (d-group, s-half, s-chunk)
    __shared__ __align__(16) u16 sP[4][2][16*40];  // per-wave, per-strip, stride 40 u16
    const int t = threadIdx.x, lane = t & 63, w = t >> 6;
    const int lr = lane & 15, qd = lane >> 4;
    const int q0 = blockIdx.x * 128;
    const int h = blockIdx.y, b = blockIdx.z;
    const size_t bhS = ((size_t)b * H_ + h) * S_;
    const size_t bhD = ((size_t)b * H_ + h) * 64;
    // Q fragments: strip p covers q rows [q0 + p*64 + w*16, +16)
    bf16x8 qf[2][2];
    #pragma unroll
    for (int p = 0; p < 2; p++) {
        const size_t qa = (bhS + q0 + p*64 + w*16 + lr) * 64 + qd * 8;
        qf[p][0] = *(const bf16x8*)&Q[qa];
        qf[p][1] = *(const bf16x8*)&Q[qa + 32];
    }
    f32x4 O[2][4] = {};
    float lsum[2][4] = {};
    for (int j0 = 0; j0 < S_; j0 += 64) {
        // stage K and V tiles, frag-major, via per-lane global_load_lds
        #pragma unroll
        for (int it = 0; it < 2; it++) {
            const int CH = (it*4 + w)*4 + qd;
            const int sbs = CH >> 3;
            const int doff = ((CH >> 2) & 1)*32 + (CH & 3)*8;
            gl2lds16(&K [(bhS + j0 + sbs*16 + lr)*64 + doff],
                     (char*)sK + (it*4 + w)*1024);
            gl2lds16(&Vt[(bhD + sbs*16 + lr)*S_ + j0 + doff],
                     (char*)sV + (it*4 + w)*1024);
        }
        __syncthreads();
        // S = Q K^T for both strips (K frags shared)
        f32x4 Sv[2][4];
        #pragma unroll
        for (int sb = 0; sb < 4; sb++) {
            bf16x8 k0 = *(const bf16x8*)&sK[(sb*8 + qd)*128 + lr*8];
            bf16x8 k1 = *(const bf16x8*)&sK[(sb*8 + 4 + qd)*128 + lr*8];
            f32x4 a0 = {}, a1 = {};
            a0 = MFMA16(qf[0][0], k0, a0);
            a0 = MFMA16(qf[0][1], k1, a0);
            a1 = MFMA16(qf[1][0], k0, a1);
            a1 = MFMA16(qf[1][1], k1, a1);
            Sv[0][sb] = a0;
            Sv[1][sb] = a1;
        }
        // no-max softmax: p = exp(s/8); lane-local partial sums
        #pragma unroll
        for (int p = 0; p < 2; p++) {
            float ps[4] = {};
            #pragma unroll
            for (int sb = 0; sb < 4; sb++)
                #pragma unroll
                for (int r = 0; r < 4; r++) {
                    const float pv = __expf(Sv[p][sb][r] * 0.125f);
                    ps[r] += pv;
                    sP[w][p][(qd*4 + r)*40 + sb*16 + lr] = f2bf(pv);
                }
            #pragma unroll
            for (int r = 0; r < 4; r++) lsum[p][r] += ps[r];
        }
        // PV (P round-trips LDS: C-layout -> A-layout)
        #pragma unroll
        for (int p = 0; p < 2; p++) {
            bf16x8 p0 = *(const bf16x8*)&sP[w][p][lr*40 + qd*8];
            bf16x8 p1 = *(const bf16x8*)&sP[w][p][lr*40 + 32 + qd*8];
            #pragma unroll
            for (int ds = 0; ds < 4; ds++) {
                bf16x8 v0 = *(const bf16x8*)&sV[(ds*8 + qd)*128 + lr*8];
                bf16x8 v1 = *(const bf16x8*)&sV[(ds*8 + 4 + qd)*128 + lr*8];
                O[p][ds] = MFMA16(p0, v0, O[p][ds]);
                O[p][ds] = MFMA16(p1, v1, O[p][ds]);
            }
        }
        __syncthreads();
    }
    // reduce lsum across the 16 lr lanes (bits 0..3)
    float linv[2][4];
    #pragma unroll
    for (int p = 0; p < 2; p++)
        #pragma unroll
        for (int r = 0; r < 4; r++) {
            float s2 = lsum[p][r];
            s2 += __shfl_xor(s2, 1, 64);
            s2 += __shfl_xor(s2, 2, 64);
            s2 += __shfl_xor(s2, 4, 64);
            s2 += __shfl_xor(s2, 8, 64);
            linv[p][r] = 1.f / s2;
        }
    #pragma unroll
    for (int p = 0; p < 2; p++)
        #pragma unroll
        for (int ds = 0; ds < 4; ds++)
            #pragma unroll
            for (int r = 0; r < 4; r++) {
                const int q = q0 + p*64 + w*16 + qd*4 + r;
                const size_t o = (size_t)(b*S_ + q)*E_ + h*64 + ds*16 + lr;
                const float val = O[p][ds][r] * linv[p][r];
                attn_bf[o]  = f2bf(val);
                attn_f32[o] = val;
            }
}

// ---------------------------------------------------------------------------
// Gate logits (fp32) -> softmax -> top2. NO atomics (writes eidx/gval only).
// One wave per token (4 tokens per block).
// ---------------------------------------------------------------------------
__global__ __launch_bounds__(256) void gate_topk_kernel(
    const float* __restrict__ attn_f32, const float* __restrict__ gate_w,
    const float* __restrict__ gate_b, float* __restrict__ gval,
    int* __restrict__ eidx)
{
    const int t = threadIdx.x;
    const int token = blockIdx.x * 4 + (t >> 6);
    const int lane  = t & 63;
    const float* a = attn_f32 + (size_t)token * E_;
    float part[NE_] = {};
    for (int i = lane; i < E_; i += 64) {
        const float av = a[i];
        #pragma unroll
        for (int n = 0; n < NE_; n++) part[n] += av * gate_w[n*E_ + i];
    }
    #pragma unroll
    for (int n = 0; n < NE_; n++) {
        #pragma unroll
        for (int off = 32; off >= 1; off >>= 1)
            part[n] += __shfl_down(part[n], off, 64);
    }
    if (lane == 0) {
        float lg[NE_];
        #pragma unroll
        for (int n = 0; n < NE_; n++) lg[n] = part[n] + gate_b[n];
        float m = lg[0];
        #pragma unroll
        for (int n = 1; n < NE_; n++) m = fmaxf(m, lg[n]);
        float ex[NE_], ssum = 0.f;
        #pragma unroll
        for (int n = 0; n < NE_; n++) { ex[n] = __expf(lg[n]-m); ssum += ex[n]; }
        const float invs = 1.f / ssum;
        int i0 = 0;
        #pragma unroll
        for (int n = 1; n < NE_; n++) if (lg[n] > lg[i0]) i0 = n;
        int i1 = (i0 == 0) ? 1 : 0;
        #pragma unroll
        for (int n = 0; n < NE_; n++) if (n != i0 && lg[n] > lg[i1]) i1 = n;
        eidx[token*2]     = i0;
        gval[token*2]     = ex[i0]*invs;
        eidx[token*2 + 1] = i1;
        gval[token*2 + 1] = ex[i1]*invs;
    }
}

// ---------------------------------------------------------------------------
// Build per-expert token lists: LDS histogram per block (512 entries),
// then 8 global atomics per block to reserve ranges, then scatter.
// ---------------------------------------------------------------------------
__global__ __launch_bounds__(256) void build_lists_kernel(
    const int* __restrict__ eidx, int* __restrict__ list, int* __restrict__ counts)
{
    __shared__ int lcnt[NE_], lbase[NE_];
    const int t = threadIdx.x;
    if (t < NE_) lcnt[t] = 0;
    __syncthreads();
    const int ent = blockIdx.x * 512 + t * 2;
    const int e0 = eidx[ent], e1 = eidx[ent + 1];
    const int p0 = atomicAdd(&lcnt[e0], 1);
    const int p1 = atomicAdd(&lcnt[e1], 1);
    __syncthreads();
    if (t < NE_) lbase[t] = atomicAdd(&counts[t], lcnt[t]);
    __syncthreads();
    list[e0 * TOKENS + lbase[e0] + p0] = ent;
    list[e1 * TOKENS + lbase[e1] + p1] = ent + 1;
}

// ---------------------------------------------------------------------------
// Gathered expert GEMM (bf16): sel[ent] = g * (attn[tok] @ ew[e]^T + eb[e])
// ---------------------------------------------------------------------------
__global__ __launch_bounds__(256,2) void gemm_expert(
    const u16* __restrict__ Abf, const u16* __restrict__ ewh,
    const float* __restrict__ eb, const int* __restrict__ list,
    const int* __restrict__ counts, const float* __restrict__ gval,
    u16* __restrict__ sel)
{
    const int e = blockIdx.z;
    const int cnt = counts[e];
    const int m0 = blockIdx.y * 128;
    if (m0 >= cnt) return;
    __shared__ __align__(16) u16 sA[128*32], sB[128*32];
    __shared__ int sEnt[128];
    const int t = threadIdx.x;
    if (t < 128) sEnt[t] = (m0 + t < cnt) ? list[e * TOKENS + m0 + t] : -1;
    __syncthreads();
    const int n0 = blockIdx.x * 128;
    const int lane = t & 63, w = t >> 6;
    const int wm = w >> 1, wn = w & 1;
    const int lr = lane & 15, qd = lane >> 4;
    const int e0 = sEnt[t >> 2], e1 = sEnt[64 + (t >> 2)];
    const u16* ga0 = Abf + (size_t)(e0 < 0 ? 0 : (e0 >> 1)) * E_ + (t & 3) * 8;
    const u16* ga1 = Abf + (size_t)(e1 < 0 ? 0 : (e1 >> 1)) * E_ + (t & 3) * 8;
    const u16* gb0 = ewh + (size_t)e * E_ * E_ + (size_t)(n0 + (t >> 2)) * E_ + (t & 3) * 8;
    const u16* gb1 = gb0 + 64 * E_;
    f32x4 acc[4][4] = {};
    for (int k0 = 0; k0 < E_; k0 += 32) {
        {
            const int l0 = (t & 192) * 16;
            const int l1 = (256 + (t & 192)) * 16;
            gl2lds16(ga0 + k0, (char*)sA + l0);
            gl2lds16(ga1 + k0, (char*)sA + l1);
            gl2lds16(gb0 + k0, (char*)sB + l0);
            gl2lds16(gb1 + k0, (char*)sB + l1);
        }
        __syncthreads();
        bf16x8 af[4], bfr[4];
        #pragma unroll
        for (int i = 0; i < 4; i++) {
            af[i]  = *(const bf16x8*)&sA[(wm*64 + i*16 + lr)*32 + qd*8];
            bfr[i] = *(const bf16x8*)&sB[(wn*64 + i*16 + lr)*32 + qd*8];
        }
        #pragma unroll
        for (int i = 0; i < 4; i++)
            #pragma unroll
            for (int j = 0; j < 4; j++)
                acc[i][j] = MFMA16(af[i], bfr[j], acc[i][j]);
        __syncthreads();
    }
    #pragma unroll
    for (int i = 0; i < 4; i++)
        #pragma unroll
        for (int r = 0; r < 4; r++) {
            const int local = wm*64 + i*16 + qd*4 + r;
            const int ent = sEnt[local];
            if (ent < 0) continue;
            const float g = gval[ent];
            #pragma unroll
            for (int j = 0; j < 4; j++) {
                const int col = n0 + wn*64 + j*16 + lr;
                sel[(size_t)ent * E_ + col] = f2bf((acc[i][j][r] + eb[e * E_ + col]) * g);
            }
        }
}

// ---------------------------------------------------------------------------
// moe[tok] = sel[tok*2] + sel[tok*2+1]  (bf16 in/out)
// ---------------------------------------------------------------------------
__global__ void combine_kernel(const u16* __restrict__ sel, u16* __restrict__ moe)
{
    const int g = blockIdx.x * 256 + threadIdx.x;
    const int tok = g >> 8;
    const int c = (g & 255) * 4;
    const u16* a = sel + (size_t)tok * 2048 + c;
    float o[4];
    #pragma unroll
    for (int j = 0; j < 4; j++) o[j] = bf2f(a[j]) + bf2f(a[1024 + j]);
    ushort4 R = {f2bf(o[0]), f2bf(o[1]), f2bf(o[2]), f2bf(o[3])};
    *(ushort4*)(moe + (size_t)tok * E_ + c) = R;
}

// ---------------------------------------------------------------------------
// FFN GEMM (bf16) + bias + fp32 residual -> fp32 out
// ---------------------------------------------------------------------------
__global__ __launch_bounds__(256,2) void gemm_ffn(
    const u16* __restrict__ Ah, const u16* __restrict__ Bh,
    const float* __restrict__ bias, const float* __restrict__ res,
    float* __restrict__ C)
{
    __shared__ __align__(16) u16 sA[128*32], sB[128*32];
    const int t = threadIdx.x;
    const int m0 = blockIdx.y * 128, n0 = blockIdx.x * 128;
    const int lane = t & 63, w = t >> 6;
    const int wm = w >> 1, wn = w & 1;
    const int lr = lane & 15, qd = lane >> 4;
    f32x4 acc[4][4] = {};
    const size_t gA = (size_t)(m0 + (t >> 2)) * E_ + (t & 3) * 8;
    const size_t gB = (size_t)(n0 + (t >> 2)) * E_ + (t & 3) * 8;
    for (int k0 = 0; k0 < E_; k0 += 32) {
        #pragma unroll
        for (int is = 0; is < 2; is++) {
            const int ldo = (is * 256 + (t & 192)) * 16;
            const size_t ro = (size_t)is * 64 * E_;
            gl2lds16(Ah + gA + ro + k0, (char*)sA + ldo);
            gl2lds16(Bh + gB + ro + k0, (char*)sB + ldo);
        }
        __syncthreads();
        bf16x8 af[4], bfr[4];
        #pragma unroll
        for (int i = 0; i < 4; i++) {
            af[i]  = *(const bf16x8*)&sA[(wm*64 + i*16 + lr)*32 + qd*8];
            bfr[i] = *(const bf16x8*)&sB[(wn*64 + i*16 + lr)*32 + qd*8];
        }
        #pragma unroll
        for (int i = 0; i < 4; i++)
            #pragma unroll
            for (int j = 0; j < 4; j++)
                acc[i][j] = MFMA16(af[i], bfr[j], acc[i][j]);
        __syncthreads();
    }
    #pragma unroll
    for (int i = 0; i < 4; i++)
        #pragma unroll
        for (int r = 0; r < 4; r++) {
            const int tok = m0 + wm*64 + i*16 + qd*4 + r;
            #pragma unroll
            for (int j = 0; j < 4; j++) {
                const int col = n0 + wn*64 + j*16 + lr;
                C[(size_t)tok * E_ + col] = acc[i][j][r] + bias[col] + res[(size_t)tok * E_ + col];
            }
        }
}

// ---------------------------------------------------------------------------
extern "C" void kernel_launch(void* const* d_in, const int* in_sizes, int n_in,
                              void* d_out, int out_size, void* d_ws, size_t ws_size,
                              hipStream_t stream) {
    const float* x      = (const float*)d_in[0];
    const float* q_w    = (const float*)d_in[1];
    const float* q_b    = (const float*)d_in[2];
    const float* k_w    = (const float*)d_in[3];
    const float* k_b    = (const float*)d_in[4];
    const float* v_w    = (const float*)d_in[5];
    const float* v_b    = (const float*)d_in[6];
    const float* gate_w = (const float*)d_in[7];
    const float* gate_b = (const float*)d_in[8];
    const float* ew     = (const float*)d_in[9];
    const float* eb     = (const float*)d_in[10];
    const float* ffn_w  = (const float*)d_in[11];
    const float* ffn_b  = (const float*)d_in[12];
    float* out = (float*)d_out;

    char* p = (char*)d_ws;
    auto alloc = [&](size_t bytes) { char* r = p; p += (bytes + 255) & ~(size_t)255; return r; };
    u16* xh   = (u16*)alloc((size_t)TOKENS*E_*2);
    u16* qwh  = (u16*)alloc((size_t)E_*E_*2);
    u16* kwh  = (u16*)alloc((size_t)E_*E_*2);
    u16* vwh  = (u16*)alloc((size_t)E_*E_*2);
    u16* fwh  = (u16*)alloc((size_t)E_*E_*2);
    u16* ewh  = (u16*)alloc((size_t)NE_*E_*E_*2);
    u16* Qhb  = (u16*)alloc((size_t)TOKENS*E_*2);
    u16* Khb  = (u16*)alloc((size_t)TOKENS*E_*2);
    u16* Vtb  = (u16*)alloc((size_t)TOKENS*E_*2);
    u16* abf  = (u16*)alloc((size_t)TOKENS*E_*2);
    float* af32 = (float*)alloc((size_t)TOKENS*E_*4);
    u16* selb = (u16*)alloc((size_t)2*TOKENS*E_*2);
    u16* moeb = (u16*)alloc((size_t)TOKENS*E_*2);
    float* gvl = (float*)alloc((size_t)2*TOKENS*4);
    int*   eix = (int*)alloc((size_t)2*TOKENS*4);
    int*   lst = (int*)alloc((size_t)NE_*TOKENS*4);
    int*   cnt = (int*)alloc(256);

    hipMemsetAsync(cnt, 0, 256, stream);

    cvt_plain_k<<<4096, 256, 0, stream>>>(x, xh, TOKENS*E_/4);
    cvt_plain_k<<<1024, 256, 0, stream>>>(q_w, qwh, E_*E_/4);
    cvt_plain_k<<<1024, 256, 0, stream>>>(k_w, kwh, E_*E_/4);
    cvt_plain_k<<<1024, 256, 0, stream>>>(v_w, vwh, E_*E_/4);
    cvt_plain_k<<<1024, 256, 0, stream>>>(ffn_w, fwh, E_*E_/4);
    cvt_plain_k<<<8192, 256, 0, stream>>>(ew, ewh, NE_*E_*E_/4);

    gemm_qk_rope<<<dim3(8,32), 256, 0, stream>>>(xh, qwh, q_b, Qhb);
    gemm_qk_rope<<<dim3(8,32), 256, 0, stream>>>(xh, kwh, k_b, Khb);
    gemm_v<<<dim3(8,32), 256, 0, stream>>>(xh, vwh, v_b, Vtb);

    attn_kernel<<<dim3(16,16,2), 256, 0, stream>>>(Qhb, Khb, Vtb, abf, af32);

    gate_topk_kernel<<<TOKENS/4, 256, 0, stream>>>(af32, gate_w, gate_b, gvl, eix);
    build_lists_kernel<<<TOKENS/256, 256, 0, stream>>>(eix, lst, cnt);
    gemm_expert<<<dim3(8,32,8), 256, 0, stream>>>(abf, ewh, eb, lst, cnt, gvl, selb);
    combine_kernel<<<4096, 256, 0, stream>>>(selb, moeb);
    gemm_ffn<<<dim3(8,32), 256, 0, stream>>>(moeb, fwh, ffn_b, x, out);
}

// Round 5
// 317.898 us; speedup vs baseline: 5.9588x; 1.1519x over previous
//
#include <hip/hip_runtime.h>
#include <hip/hip_bf16.h>

#define B_ 2
#define S_ 2048
#define E_ 1024
#define H_ 16
#define D_ 64
#define NE_ 8
#define TOKENS (B_*S_)   // 4096

typedef __attribute__((ext_vector_type(8))) short bf16x8;
typedef __attribute__((ext_vector_type(4))) float f32x4;
typedef unsigned short u16;
typedef unsigned int u32;

__device__ __forceinline__ u16 f2bf(float f) {
    u32 u = __float_as_uint(f);
    u32 r = u + 0x7fffu + ((u >> 16) & 1u);
    return (u16)(r >> 16);
}
__device__ __forceinline__ float bf2f(u16 h) {
    return __uint_as_float(((u32)h) << 16);
}
__device__ __forceinline__ void gl2lds16(const void* g, void* l) {
    __builtin_amdgcn_global_load_lds(
        (__attribute__((address_space(1))) void*)(g),
        (__attribute__((address_space(3))) void*)(l), 16, 0, 0);
}
#define MFMA16(a,b,c) __builtin_amdgcn_mfma_f32_16x16x32_bf16(a,b,c,0,0,0)

// ---------------------------------------------------------------------------
// Fused fp32 -> bf16 conversion for all six tensors (one dispatch).
// Segments (in 256-float4 blocks): x 4096 | qw 1024 | kw 1024 | vw 1024 |
// fw 1024 | ew 8192  -> 16384 blocks total.
// ---------------------------------------------------------------------------
__global__ void cvt_all_k(
    const float* __restrict__ x,  const float* __restrict__ qw,
    const float* __restrict__ kw, const float* __restrict__ vw,
    const float* __restrict__ fw, const float* __restrict__ ew,
    u16* __restrict__ xh,  u16* __restrict__ qwh, u16* __restrict__ kwh,
    u16* __restrict__ vwh, u16* __restrict__ fwh, u16* __restrict__ ewh)
{
    const int blk = blockIdx.x;
    const float* s; u16* d; int off;
    if (blk < 4096)      { s = x;  d = xh;  off = blk; }
    else if (blk < 5120) { s = qw; d = qwh; off = blk - 4096; }
    else if (blk < 6144) { s = kw; d = kwh; off = blk - 5120; }
    else if (blk < 7168) { s = vw; d = vwh; off = blk - 6144; }
    else if (blk < 8192) { s = fw; d = fwh; off = blk - 7168; }
    else                 { s = ew; d = ewh; off = blk - 8192; }
    const size_t i = (size_t)off * 256 + threadIdx.x;
    const float4 v = *(const float4*)(s + i * 4);
    ushort4 H = {f2bf(v.x), f2bf(v.y), f2bf(v.z), f2bf(v.w)};
    *(ushort4*)(d + i * 4) = H;
}

// ---------------------------------------------------------------------------
// RoPE cos/sin table: tab[s*32 + d1] = {cos, sin}(s * 10000^(-d1/32))
// ---------------------------------------------------------------------------
__global__ void rope_tab_kernel(float2* __restrict__ tab)
{
    const int idx = blockIdx.x * 256 + threadIdx.x;   // < 65536
    const int s = idx >> 5, d1 = idx & 31;
    const float inv = exp2f(-(float)d1 * 0.41524101186091903f); // log2(1e4)/32
    float sn, cs;
    sincosf((float)s * inv, &sn, &cs);
    tab[idx] = make_float2(cs, sn);
}

// ---------------------------------------------------------------------------
// Fused Q/K/V projection GEMM (z selects weight). 128x128 tile, BK=32.
// z<2: RoPE (table) epilogue, head-major [b][h][s][d] bf16.
// z=2: transposed store Vt[b][h][d][s].
// ---------------------------------------------------------------------------
__global__ __launch_bounds__(256,2) void gemm_qkv(
    const u16* __restrict__ Ah,
    const u16* __restrict__ qwh, const u16* __restrict__ kwh,
    const u16* __restrict__ vwh,
    const float* __restrict__ q_b, const float* __restrict__ k_b,
    const float* __restrict__ v_b,
    const float2* __restrict__ tab,
    u16* __restrict__ Qhb, u16* __restrict__ Khb, u16* __restrict__ Vtb)
{
    __shared__ __align__(16) u16 sA[128*32], sB[128*32];
    const int z = blockIdx.z;
    const u16* Bh = (z == 0) ? qwh : (z == 1) ? kwh : vwh;
    const float* bias = (z == 0) ? q_b : (z == 1) ? k_b : v_b;
    const int t = threadIdx.x;
    const int m0 = blockIdx.y * 128, n0 = blockIdx.x * 128;
    const int lane = t & 63, w = t >> 6;
    const int wm = w >> 1, wn = w & 1;
    const int lr = lane & 15, qd = lane >> 4;
    f32x4 acc[4][4] = {};
    const size_t gA = (size_t)(m0 + (t >> 2)) * E_ + (t & 3) * 8;
    const size_t gB = (size_t)(n0 + (t >> 2)) * E_ + (t & 3) * 8;
    for (int k0 = 0; k0 < E_; k0 += 32) {
        #pragma unroll
        for (int is = 0; is < 2; is++) {
            const int ldo = (is * 256 + (t & 192)) * 16;
            const size_t ro = (size_t)is * 64 * E_;
            gl2lds16(Ah + gA + ro + k0, (char*)sA + ldo);
            gl2lds16(Bh + gB + ro + k0, (char*)sB + ldo);
        }
        __syncthreads();
        bf16x8 af[4], bfr[4];
        #pragma unroll
        for (int i = 0; i < 4; i++) {
            af[i]  = *(const bf16x8*)&sA[(wm*64 + i*16 + lr)*32 + qd*8];
            bfr[i] = *(const bf16x8*)&sB[(wn*64 + i*16 + lr)*32 + qd*8];
        }
        #pragma unroll
        for (int i = 0; i < 4; i++)
            #pragma unroll
            for (int j = 0; j < 4; j++)
                acc[i][j] = MFMA16(af[i], bfr[j], acc[i][j]);
        __syncthreads();
    }
    const int head = (n0 + wn * 64) >> 6;
    if (z < 2) {
        u16* Oh = (z == 0) ? Qhb : Khb;
        #pragma unroll
        for (int j = 0; j < 2; j++) {
            const int d1 = j * 16 + lr;
            const float b1 = bias[head * 64 + d1];
            const float b2 = bias[head * 64 + d1 + 32];
            #pragma unroll
            for (int i = 0; i < 4; i++) {
                #pragma unroll
                for (int r = 0; r < 4; r++) {
                    const int tok = m0 + wm*64 + i*16 + qd*4 + r;
                    const int bb = tok >> 11, ss = tok & (S_ - 1);
                    const float2 t2 = tab[ss * 32 + d1];
                    const float q1 = acc[i][j][r]   + b1;
                    const float q2 = acc[i][j+2][r] + b2;
                    const size_t o = (((size_t)bb * H_ + head) * S_ + ss) * 64 + d1;
                    Oh[o]    = f2bf(q1 * t2.x - q2 * t2.y);
                    Oh[o+32] = f2bf(q2 * t2.x + q1 * t2.y);
                }
            }
        }
    } else {
        #pragma unroll
        for (int j = 0; j < 4; j++) {
            const int d = j * 16 + lr;
            const float bv = bias[head * 64 + d];
            #pragma unroll
            for (int i = 0; i < 4; i++)
                #pragma unroll
                for (int r = 0; r < 4; r++) {
                    const int tok = m0 + wm*64 + i*16 + qd*4 + r;
                    const int bb = tok >> 11, ss = tok & (S_ - 1);
                    Vtb[(((size_t)bb * H_ + head) * 64 + d) * S_ + ss] = f2bf(acc[i][j][r] + bv);
                }
        }
    }
}

// ---------------------------------------------------------------------------
// Flash attention, bf16 MFMA, fragment-major LDS (conflict-free reads).
// Block = (b, h, 64 queries), 4 waves x 16 q-rows; 4 blocks/CU.
// No-max softmax; lane-local lsum reduced once at end.
// ---------------------------------------------------------------------------
__global__ __launch_bounds__(256,4) void attn_kernel(
    const u16* __restrict__ Q, const u16* __restrict__ K,
    const u16* __restrict__ Vt,
    u16* __restrict__ attn_bf, float* __restrict__ attn_f32)
{
    __shared__ __align__(16) u16 sK[64*64];      // frag-major
    __shared__ __align__(16) u16 sV[64*64];      // frag-major
    __shared__ __align__(16) u16 sP[4][16*40];   // per-wave, stride 40 u16
    const int t = threadIdx.x, lane = t & 63, w = t >> 6;
    const int lr = lane & 15, qd = lane >> 4;
    const int q0 = blockIdx.x * 64;
    const int h = blockIdx.y, b = blockIdx.z;
    const size_t bhS = ((size_t)b * H_ + h) * S_;
    const size_t bhD = ((size_t)b * H_ + h) * 64;
    bf16x8 qf0, qf1;
    {
        const size_t qa = (bhS + q0 + w * 16 + lr) * 64 + qd * 8;
        qf0 = *(const bf16x8*)&Q[qa];
        qf1 = *(const bf16x8*)&Q[qa + 32];
    }
    f32x4 O[4] = {};
    float lsum[4] = {};
    for (int j0 = 0; j0 < S_; j0 += 64) {
        // stage K and V tiles, frag-major, via per-lane global_load_lds
        #pragma unroll
        for (int it = 0; it < 2; it++) {
            const int CH = (it*4 + w)*4 + qd;
            const int sbs = CH >> 3;
            const int doff = ((CH >> 2) & 1)*32 + (CH & 3)*8;
            gl2lds16(&K [(bhS + j0 + sbs*16 + lr)*64 + doff],
                     (char*)sK + (it*4 + w)*1024);
            gl2lds16(&Vt[(bhD + sbs*16 + lr)*S_ + j0 + doff],
                     (char*)sV + (it*4 + w)*1024);
        }
        __syncthreads();
        // S = Q K^T
        f32x4 Sv[4];
        #pragma unroll
        for (int sb = 0; sb < 4; sb++) {
            bf16x8 k0 = *(const bf16x8*)&sK[(sb*8 + qd)*128 + lr*8];
            bf16x8 k1 = *(const bf16x8*)&sK[(sb*8 + 4 + qd)*128 + lr*8];
            f32x4 a = {};
            a = MFMA16(qf0, k0, a);
            a = MFMA16(qf1, k1, a);
            Sv[sb] = a;
        }
        // no-max softmax: p = exp(s/8); lane-local partial sums
        float ps[4] = {};
        #pragma unroll
        for (int sb = 0; sb < 4; sb++)
            #pragma unroll
            for (int r = 0; r < 4; r++) {
                const float pv = __expf(Sv[sb][r] * 0.125f);
                ps[r] += pv;
                sP[w][(qd*4 + r)*40 + sb*16 + lr] = f2bf(pv);
            }
        #pragma unroll
        for (int r = 0; r < 4; r++) lsum[r] += ps[r];
        // PV (P round-trips LDS: C-layout -> A-layout; same-wave, no barrier)
        bf16x8 p0 = *(const bf16x8*)&sP[w][lr*40 + qd*8];
        bf16x8 p1 = *(const bf16x8*)&sP[w][lr*40 + 32 + qd*8];
        #pragma unroll
        for (int ds = 0; ds < 4; ds++) {
            bf16x8 v0 = *(const bf16x8*)&sV[(ds*8 + qd)*128 + lr*8];
            bf16x8 v1 = *(const bf16x8*)&sV[(ds*8 + 4 + qd)*128 + lr*8];
            O[ds] = MFMA16(p0, v0, O[ds]);
            O[ds] = MFMA16(p1, v1, O[ds]);
        }
        __syncthreads();
    }
    float linv[4];
    #pragma unroll
    for (int r = 0; r < 4; r++) {
        float s2 = lsum[r];
        s2 += __shfl_xor(s2, 1, 64);
        s2 += __shfl_xor(s2, 2, 64);
        s2 += __shfl_xor(s2, 4, 64);
        s2 += __shfl_xor(s2, 8, 64);
        linv[r] = 1.f / s2;
    }
    #pragma unroll
    for (int ds = 0; ds < 4; ds++)
        #pragma unroll
        for (int r = 0; r < 4; r++) {
            const int q = q0 + w * 16 + qd * 4 + r;
            const size_t o = (size_t)(b*S_ + q)*E_ + h*64 + ds*16 + lr;
            const float val = O[ds][r] * linv[r];
            attn_bf[o]  = f2bf(val);
            attn_f32[o] = val;
        }
}

// ---------------------------------------------------------------------------
// Gate logits (fp32) -> softmax -> top2. NO atomics (writes eidx/gval only).
// ---------------------------------------------------------------------------
__global__ __launch_bounds__(256) void gate_topk_kernel(
    const float* __restrict__ attn_f32, const float* __restrict__ gate_w,
    const float* __restrict__ gate_b, float* __restrict__ gval,
    int* __restrict__ eidx)
{
    const int t = threadIdx.x;
    const int token = blockIdx.x * 4 + (t >> 6);
    const int lane  = t & 63;
    const float* a = attn_f32 + (size_t)token * E_;
    float part[NE_] = {};
    for (int i = lane; i < E_; i += 64) {
        const float av = a[i];
        #pragma unroll
        for (int n = 0; n < NE_; n++) part[n] += av * gate_w[n*E_ + i];
    }
    #pragma unroll
    for (int n = 0; n < NE_; n++) {
        #pragma unroll
        for (int off = 32; off >= 1; off >>= 1)
            part[n] += __shfl_down(part[n], off, 64);
    }
    if (lane == 0) {
        float lg[NE_];
        #pragma unroll
        for (int n = 0; n < NE_; n++) lg[n] = part[n] + gate_b[n];
        float m = lg[0];
        #pragma unroll
        for (int n = 1; n < NE_; n++) m = fmaxf(m, lg[n]);
        float ex[NE_], ssum = 0.f;
        #pragma unroll
        for (int n = 0; n < NE_; n++) { ex[n] = __expf(lg[n]-m); ssum += ex[n]; }
        const float invs = 1.f / ssum;
        int i0 = 0;
        #pragma unroll
        for (int n = 1; n < NE_; n++) if (lg[n] > lg[i0]) i0 = n;
        int i1 = (i0 == 0) ? 1 : 0;
        #pragma unroll
        for (int n = 0; n < NE_; n++) if (n != i0 && lg[n] > lg[i1]) i1 = n;
        eidx[token*2]     = i0;
        gval[token*2]     = ex[i0]*invs;
        eidx[token*2 + 1] = i1;
        gval[token*2 + 1] = ex[i1]*invs;
    }
}

// ---------------------------------------------------------------------------
// Build per-expert token lists: LDS histogram per block (512 entries),
// then 8 global atomics per block to reserve ranges, then scatter.
// ---------------------------------------------------------------------------
__global__ __launch_bounds__(256) void build_lists_kernel(
    const int* __restrict__ eidx, int* __restrict__ list, int* __restrict__ counts)
{
    __shared__ int lcnt[NE_], lbase[NE_];
    const int t = threadIdx.x;
    if (t < NE_) lcnt[t] = 0;
    __syncthreads();
    const int ent = blockIdx.x * 512 + t * 2;
    const int e0 = eidx[ent], e1 = eidx[ent + 1];
    const int p0 = atomicAdd(&lcnt[e0], 1);
    const int p1 = atomicAdd(&lcnt[e1], 1);
    __syncthreads();
    if (t < NE_) lbase[t] = atomicAdd(&counts[t], lcnt[t]);
    __syncthreads();
    list[e0 * TOKENS + lbase[e0] + p0] = ent;
    list[e1 * TOKENS + lbase[e1] + p1] = ent + 1;
}

// ---------------------------------------------------------------------------
// Gathered expert GEMM (bf16): sel[ent] = g * (attn[tok] @ ew[e]^T + eb[e])
// ---------------------------------------------------------------------------
__global__ __launch_bounds__(256,2) void gemm_expert(
    const u16* __restrict__ Abf, const u16* __restrict__ ewh,
    const float* __restrict__ eb, const int* __restrict__ list,
    const int* __restrict__ counts, const float* __restrict__ gval,
    u16* __restrict__ sel)
{
    const int e = blockIdx.z;
    const int cnt = counts[e];
    const int m0 = blockIdx.y * 128;
    if (m0 >= cnt) return;
    __shared__ __align__(16) u16 sA[128*32], sB[128*32];
    __shared__ int sEnt[128];
    const int t = threadIdx.x;
    if (t < 128) sEnt[t] = (m0 + t < cnt) ? list[e * TOKENS + m0 + t] : -1;
    __syncthreads();
    const int n0 = blockIdx.x * 128;
    const int lane = t & 63, w = t >> 6;
    const int wm = w >> 1, wn = w & 1;
    const int lr = lane & 15, qd = lane >> 4;
    const int e0 = sEnt[t >> 2], e1 = sEnt[64 + (t >> 2)];
    const u16* ga0 = Abf + (size_t)(e0 < 0 ? 0 : (e0 >> 1)) * E_ + (t & 3) * 8;
    const u16* ga1 = Abf + (size_t)(e1 < 0 ? 0 : (e1 >> 1)) * E_ + (t & 3) * 8;
    const u16* gb0 = ewh + (size_t)e * E_ * E_ + (size_t)(n0 + (t >> 2)) * E_ + (t & 3) * 8;
    const u16* gb1 = gb0 + 64 * E_;
    f32x4 acc[4][4] = {};
    for (int k0 = 0; k0 < E_; k0 += 32) {
        {
            const int l0 = (t & 192) * 16;
            const int l1 = (256 + (t & 192)) * 16;
            gl2lds16(ga0 + k0, (char*)sA + l0);
            gl2lds16(ga1 + k0, (char*)sA + l1);
            gl2lds16(gb0 + k0, (char*)sB + l0);
            gl2lds16(gb1 + k0, (char*)sB + l1);
        }
        __syncthreads();
        bf16x8 af[4], bfr[4];
        #pragma unroll
        for (int i = 0; i < 4; i++) {
            af[i]  = *(const bf16x8*)&sA[(wm*64 + i*16 + lr)*32 + qd*8];
            bfr[i] = *(const bf16x8*)&sB[(wn*64 + i*16 + lr)*32 + qd*8];
        }
        #pragma unroll
        for (int i = 0; i < 4; i++)
            #pragma unroll
            for (int j = 0; j < 4; j++)
                acc[i][j] = MFMA16(af[i], bfr[j], acc[i][j]);
        __syncthreads();
    }
    #pragma unroll
    for (int i = 0; i < 4; i++)
        #pragma unroll
        for (int r = 0; r < 4; r++) {
            const int local = wm*64 + i*16 + qd*4 + r;
            const int ent = sEnt[local];
            if (ent < 0) continue;
            const float g = gval[ent];
            #pragma unroll
            for (int j = 0; j < 4; j++) {
                const int col = n0 + wn*64 + j*16 + lr;
                sel[(size_t)ent * E_ + col] = f2bf((acc[i][j][r] + eb[e * E_ + col]) * g);
            }
        }
}

// ---------------------------------------------------------------------------
// moe[tok] = sel[tok*2] + sel[tok*2+1]  (bf16 in/out)
// ---------------------------------------------------------------------------
__global__ void combine_kernel(const u16* __restrict__ sel, u16* __restrict__ moe)
{
    const int g = blockIdx.x * 256 + threadIdx.x;
    const int tok = g >> 8;
    const int c = (g & 255) * 4;
    const u16* a = sel + (size_t)tok * 2048 + c;
    float o[4];
    #pragma unroll
    for (int j = 0; j < 4; j++) o[j] = bf2f(a[j]) + bf2f(a[1024 + j]);
    ushort4 R = {f2bf(o[0]), f2bf(o[1]), f2bf(o[2]), f2bf(o[3])};
    *(ushort4*)(moe + (size_t)tok * E_ + c) = R;
}

// ---------------------------------------------------------------------------
// FFN GEMM (bf16) + bias + fp32 residual -> fp32 out
// ---------------------------------------------------------------------------
__global__ __launch_bounds__(256,2) void gemm_ffn(
    const u16* __restrict__ Ah, const u16* __restrict__ Bh,
    const float* __restrict__ bias, const float* __restrict__ res,
    float* __restrict__ C)
{
    __shared__ __align__(16) u16 sA[128*32], sB[128*32];
    const int t = threadIdx.x;
    const int m0 = blockIdx.y * 128, n0 = blockIdx.x * 128;
    const int lane = t & 63, w = t >> 6;
    const int wm = w >> 1, wn = w & 1;
    const int lr = lane & 15, qd = lane >> 4;
    f32x4 acc[4][4] = {};
    const size_t gA = (size_t)(m0 + (t >> 2)) * E_ + (t & 3) * 8;
    const size_t gB = (size_t)(n0 + (t >> 2)) * E_ + (t & 3) * 8;
    for (int k0 = 0; k0 < E_; k0 += 32) {
        #pragma unroll
        for (int is = 0; is < 2; is++) {
            const int ldo = (is * 256 + (t & 192)) * 16;
            const size_t ro = (size_t)is * 64 * E_;
            gl2lds16(Ah + gA + ro + k0, (char*)sA + ldo);
            gl2lds16(Bh + gB + ro + k0, (char*)sB + ldo);
        }
        __syncthreads();
        bf16x8 af[4], bfr[4];
        #pragma unroll
        for (int i = 0; i < 4; i++) {
            af[i]  = *(const bf16x8*)&sA[(wm*64 + i*16 + lr)*32 + qd*8];
            bfr[i] = *(const bf16x8*)&sB[(wn*64 + i*16 + lr)*32 + qd*8];
        }
        #pragma unroll
        for (int i = 0; i < 4; i++)
            #pragma unroll
            for (int j = 0; j < 4; j++)
                acc[i][j] = MFMA16(af[i], bfr[j], acc[i][j]);
        __syncthreads();
    }
    #pragma unroll
    for (int i = 0; i < 4; i++)
        #pragma unroll
        for (int r = 0; r < 4; r++) {
            const int tok = m0 + wm*64 + i*16 + qd*4 + r;
            #pragma unroll
            for (int j = 0; j < 4; j++) {
                const int col = n0 + wn*64 + j*16 + lr;
                C[(size_t)tok * E_ + col] = acc[i][j][r] + bias[col] + res[(size_t)tok * E_ + col];
            }
        }
}

// ---------------------------------------------------------------------------
extern "C" void kernel_launch(void* const* d_in, const int* in_sizes, int n_in,
                              void* d_out, int out_size, void* d_ws, size_t ws_size,
                              hipStream_t stream) {
    const float* x      = (const float*)d_in[0];
    const float* q_w    = (const float*)d_in[1];
    const float* q_b    = (const float*)d_in[2];
    const float* k_w    = (const float*)d_in[3];
    const float* k_b    = (const float*)d_in[4];
    const float* v_w    = (const float*)d_in[5];
    const float* v_b    = (const float*)d_in[6];
    const float* gate_w = (const float*)d_in[7];
    const float* gate_b = (const float*)d_in[8];
    const float* ew     = (const float*)d_in[9];
    const float* eb     = (const float*)d_in[10];
    const float* ffn_w  = (const float*)d_in[11];
    const float* ffn_b  = (const float*)d_in[12];
    float* out = (float*)d_out;

    char* p = (char*)d_ws;
    auto alloc = [&](size_t bytes) { char* r = p; p += (bytes + 255) & ~(size_t)255; return r; };
    u16* xh   = (u16*)alloc((size_t)TOKENS*E_*2);
    u16* qwh  = (u16*)alloc((size_t)E_*E_*2);
    u16* kwh  = (u16*)alloc((size_t)E_*E_*2);
    u16* vwh  = (u16*)alloc((size_t)E_*E_*2);
    u16* fwh  = (u16*)alloc((size_t)E_*E_*2);
    u16* ewh  = (u16*)alloc((size_t)NE_*E_*E_*2);
    u16* Qhb  = (u16*)alloc((size_t)TOKENS*E_*2);
    u16* Khb  = (u16*)alloc((size_t)TOKENS*E_*2);
    u16* Vtb  = (u16*)alloc((size_t)TOKENS*E_*2);
    u16* abf  = (u16*)alloc((size_t)TOKENS*E_*2);
    float* af32 = (float*)alloc((size_t)TOKENS*E_*4);
    u16* selb = (u16*)alloc((size_t)2*TOKENS*E_*2);
    u16* moeb = (u16*)alloc((size_t)TOKENS*E_*2);
    float2* rtab = (float2*)alloc((size_t)S_*32*8);
    float* gvl = (float*)alloc((size_t)2*TOKENS*4);
    int*   eix = (int*)alloc((size_t)2*TOKENS*4);
    int*   lst = (int*)alloc((size_t)NE_*TOKENS*4);
    int*   cnt = (int*)alloc(256);

    hipMemsetAsync(cnt, 0, 256, stream);

    rope_tab_kernel<<<S_*32/256, 256, 0, stream>>>(rtab);
    cvt_all_k<<<16384, 256, 0, stream>>>(x, q_w, k_w, v_w, ffn_w, ew,
                                         xh, qwh, kwh, vwh, fwh, ewh);

    gemm_qkv<<<dim3(8,32,3), 256, 0, stream>>>(xh, qwh, kwh, vwh,
                                               q_b, k_b, v_b, rtab,
                                               Qhb, Khb, Vtb);

    attn_kernel<<<dim3(32,16,2), 256, 0, stream>>>(Qhb, Khb, Vtb, abf, af32);

    gate_topk_kernel<<<TOKENS/4, 256, 0, stream>>>(af32, gate_w, gate_b, gvl, eix);
    build_lists_kernel<<<TOKENS/256, 256, 0, stream>>>(eix, lst, cnt);
    gemm_expert<<<dim3(8,32,8), 256, 0, stream>>>(abf, ewh, eb, lst, cnt, gvl, selb);
    combine_kernel<<<4096, 256, 0, stream>>>(selb, moeb);
    gemm_ffn<<<dim3(8,32), 256, 0, stream>>>(moeb, fwh, ffn_b, x, out);
}

// Round 6
// 304.399 us; speedup vs baseline: 6.2230x; 1.0443x over previous
//
#include <hip/hip_runtime.h>
#include <hip/hip_bf16.h>

#define B_ 2
#define S_ 2048
#define E_ 1024
#define H_ 16
#define D_ 64
#define NE_ 8
#define TOKENS (B_*S_)   // 4096

typedef __attribute__((ext_vector_type(8))) short bf16x8;
typedef __attribute__((ext_vector_type(4))) float f32x4;
typedef unsigned short u16;
typedef unsigned int u32;

__device__ __forceinline__ u16 f2bf(float f) {
    u32 u = __float_as_uint(f);
    u32 r = u + 0x7fffu + ((u >> 16) & 1u);
    return (u16)(r >> 16);
}
__device__ __forceinline__ float bf2f(u16 h) {
    return __uint_as_float(((u32)h) << 16);
}
__device__ __forceinline__ void gl2lds16(const void* g, void* l) {
    __builtin_amdgcn_global_load_lds(
        (__attribute__((address_space(1))) void*)(g),
        (__attribute__((address_space(3))) void*)(l), 16, 0, 0);
}
#define MFMA16(a,b,c) __builtin_amdgcn_mfma_f32_16x16x32_bf16(a,b,c,0,0,0)

// ---------------------------------------------------------------------------
// Fused fp32 -> bf16 conversion for all six tensors (one dispatch).
// ---------------------------------------------------------------------------
__global__ void cvt_all_k(
    const float* __restrict__ x,  const float* __restrict__ qw,
    const float* __restrict__ kw, const float* __restrict__ vw,
    const float* __restrict__ fw, const float* __restrict__ ew,
    u16* __restrict__ xh,  u16* __restrict__ qwh, u16* __restrict__ kwh,
    u16* __restrict__ vwh, u16* __restrict__ fwh, u16* __restrict__ ewh)
{
    const int blk = blockIdx.x;
    const float* s; u16* d; int off;
    if (blk < 4096)      { s = x;  d = xh;  off = blk; }
    else if (blk < 5120) { s = qw; d = qwh; off = blk - 4096; }
    else if (blk < 6144) { s = kw; d = kwh; off = blk - 5120; }
    else if (blk < 7168) { s = vw; d = vwh; off = blk - 6144; }
    else if (blk < 8192) { s = fw; d = fwh; off = blk - 7168; }
    else                 { s = ew; d = ewh; off = blk - 8192; }
    const size_t i = (size_t)off * 256 + threadIdx.x;
    const float4 v = *(const float4*)(s + i * 4);
    ushort4 H = {f2bf(v.x), f2bf(v.y), f2bf(v.z), f2bf(v.w)};
    *(ushort4*)(d + i * 4) = H;
}

// ---------------------------------------------------------------------------
// RoPE cos/sin table: tab[s*32 + d1] = {cos, sin}(s * 10000^(-d1/32))
// ---------------------------------------------------------------------------
__global__ void rope_tab_kernel(float2* __restrict__ tab)
{
    const int idx = blockIdx.x * 256 + threadIdx.x;   // < 65536
    const int s = idx >> 5, d1 = idx & 31;
    const float inv = exp2f(-(float)d1 * 0.41524101186091903f); // log2(1e4)/32
    float sn, cs;
    sincosf((float)s * inv, &sn, &cs);
    tab[idx] = make_float2(cs, sn);
}

// ---------------------------------------------------------------------------
// Fused Q/K/V projection GEMM (z selects weight). 128x128 tile, BK=32.
// z<2: RoPE (table) epilogue, head-major [b][h][s][d] bf16.
// z=2: transposed store Vt[b][h][d][s].
// ---------------------------------------------------------------------------
__global__ __launch_bounds__(256,2) void gemm_qkv(
    const u16* __restrict__ Ah,
    const u16* __restrict__ qwh, const u16* __restrict__ kwh,
    const u16* __restrict__ vwh,
    const float* __restrict__ q_b, const float* __restrict__ k_b,
    const float* __restrict__ v_b,
    const float2* __restrict__ tab,
    u16* __restrict__ Qhb, u16* __restrict__ Khb, u16* __restrict__ Vtb)
{
    __shared__ __align__(16) u16 sA[128*32], sB[128*32];
    const int z = blockIdx.z;
    const u16* Bh = (z == 0) ? qwh : (z == 1) ? kwh : vwh;
    const float* bias = (z == 0) ? q_b : (z == 1) ? k_b : v_b;
    const int t = threadIdx.x;
    const int m0 = blockIdx.y * 128, n0 = blockIdx.x * 128;
    const int lane = t & 63, w = t >> 6;
    const int wm = w >> 1, wn = w & 1;
    const int lr = lane & 15, qd = lane >> 4;
    f32x4 acc[4][4] = {};
    const size_t gA = (size_t)(m0 + (t >> 2)) * E_ + (t & 3) * 8;
    const size_t gB = (size_t)(n0 + (t >> 2)) * E_ + (t & 3) * 8;
    for (int k0 = 0; k0 < E_; k0 += 32) {
        #pragma unroll
        for (int is = 0; is < 2; is++) {
            const int ldo = (is * 256 + (t & 192)) * 16;
            const size_t ro = (size_t)is * 64 * E_;
            gl2lds16(Ah + gA + ro + k0, (char*)sA + ldo);
            gl2lds16(Bh + gB + ro + k0, (char*)sB + ldo);
        }
        __syncthreads();
        bf16x8 af[4], bfr[4];
        #pragma unroll
        for (int i = 0; i < 4; i++) {
            af[i]  = *(const bf16x8*)&sA[(wm*64 + i*16 + lr)*32 + qd*8];
            bfr[i] = *(const bf16x8*)&sB[(wn*64 + i*16 + lr)*32 + qd*8];
        }
        #pragma unroll
        for (int i = 0; i < 4; i++)
            #pragma unroll
            for (int j = 0; j < 4; j++)
                acc[i][j] = MFMA16(af[i], bfr[j], acc[i][j]);
        __syncthreads();
    }
    const int head = (n0 + wn * 64) >> 6;
    if (z < 2) {
        u16* Oh = (z == 0) ? Qhb : Khb;
        #pragma unroll
        for (int j = 0; j < 2; j++) {
            const int d1 = j * 16 + lr;
            const float b1 = bias[head * 64 + d1];
            const float b2 = bias[head * 64 + d1 + 32];
            #pragma unroll
            for (int i = 0; i < 4; i++) {
                #pragma unroll
                for (int r = 0; r < 4; r++) {
                    const int tok = m0 + wm*64 + i*16 + qd*4 + r;
                    const int bb = tok >> 11, ss = tok & (S_ - 1);
                    const float2 t2 = tab[ss * 32 + d1];
                    const float q1 = acc[i][j][r]   + b1;
                    const float q2 = acc[i][j+2][r] + b2;
                    const size_t o = (((size_t)bb * H_ + head) * S_ + ss) * 64 + d1;
                    Oh[o]    = f2bf(q1 * t2.x - q2 * t2.y);
                    Oh[o+32] = f2bf(q2 * t2.x + q1 * t2.y);
                }
            }
        }
    } else {
        #pragma unroll
        for (int j = 0; j < 4; j++) {
            const int d = j * 16 + lr;
            const float bv = bias[head * 64 + d];
            #pragma unroll
            for (int i = 0; i < 4; i++)
                #pragma unroll
                for (int r = 0; r < 4; r++) {
                    const int tok = m0 + wm*64 + i*16 + qd*4 + r;
                    const int bb = tok >> 11, ss = tok & (S_ - 1);
                    Vtb[(((size_t)bb * H_ + head) * 64 + d) * S_ + ss] = f2bf(acc[i][j][r] + bv);
                }
        }
    }
}

// ---------------------------------------------------------------------------
// Flash attention, split-S partials. Block = (128 q, h, b, s-chunk of 1024).
// 4 waves x 2 strips of 16 q; K/V frag reads shared across strips.
// No-max softmax is additive across chunks -> partial O (f32) + partial lsum.
// ---------------------------------------------------------------------------
__global__ __launch_bounds__(256,4) void attn_kernel(
    const u16* __restrict__ Q, const u16* __restrict__ K,
    const u16* __restrict__ Vt,
    float* __restrict__ Opart, float* __restrict__ lpart)
{
    __shared__ __align__(16) u16 sK[64*64];        // frag-major
    __shared__ __align__(16) u16 sV[64*64];        // frag-major
    __shared__ __align__(16) u16 sP[4][2][16*40];  // per-wave, per-strip
    const int t = threadIdx.x, lane = t & 63, w = t >> 6;
    const int lr = lane & 15, qd = lane >> 4;
    const int q0 = blockIdx.x * 128;
    const int h = blockIdx.y;
    const int b = blockIdx.z & 1, sc = blockIdx.z >> 1;
    const size_t bhS = ((size_t)b * H_ + h) * S_;
    const size_t bhD = ((size_t)b * H_ + h) * 64;
    bf16x8 qf[2][2];
    #pragma unroll
    for (int p = 0; p < 2; p++) {
        const size_t qa = (bhS + q0 + p*64 + w*16 + lr) * 64 + qd * 8;
        qf[p][0] = *(const bf16x8*)&Q[qa];
        qf[p][1] = *(const bf16x8*)&Q[qa + 32];
    }
    f32x4 O[2][4] = {};
    float lsum[2][4] = {};
    const int jbeg = sc * 1024, jend = jbeg + 1024;
    for (int j0 = jbeg; j0 < jend; j0 += 64) {
        #pragma unroll
        for (int it = 0; it < 2; it++) {
            const int CH = (it*4 + w)*4 + qd;
            const int sbs = CH >> 3;
            const int doff = ((CH >> 2) & 1)*32 + (CH & 3)*8;
            gl2lds16(&K [(bhS + j0 + sbs*16 + lr)*64 + doff],
                     (char*)sK + (it*4 + w)*1024);
            gl2lds16(&Vt[(bhD + sbs*16 + lr)*S_ + j0 + doff],
                     (char*)sV + (it*4 + w)*1024);
        }
        __syncthreads();
        // S = Q K^T for both strips (K frags shared)
        {
            f32x4 Sv[2][4];
            #pragma unroll
            for (int sb = 0; sb < 4; sb++) {
                bf16x8 k0 = *(const bf16x8*)&sK[(sb*8 + qd)*128 + lr*8];
                bf16x8 k1 = *(const bf16x8*)&sK[(sb*8 + 4 + qd)*128 + lr*8];
                f32x4 a0 = {}, a1 = {};
                a0 = MFMA16(qf[0][0], k0, a0);
                a0 = MFMA16(qf[0][1], k1, a0);
                a1 = MFMA16(qf[1][0], k0, a1);
                a1 = MFMA16(qf[1][1], k1, a1);
                Sv[0][sb] = a0;
                Sv[1][sb] = a1;
            }
            // no-max softmax: p = exp(s/8)
            #pragma unroll
            for (int p = 0; p < 2; p++) {
                float ps[4] = {};
                #pragma unroll
                for (int sb = 0; sb < 4; sb++)
                    #pragma unroll
                    for (int r = 0; r < 4; r++) {
                        const float pv = __expf(Sv[p][sb][r] * 0.125f);
                        ps[r] += pv;
                        sP[w][p][(qd*4 + r)*40 + sb*16 + lr] = f2bf(pv);
                    }
                #pragma unroll
                for (int r = 0; r < 4; r++) lsum[p][r] += ps[r];
            }
        }
        // PV: V frags read ONCE, used by both strips
        {
            bf16x8 vv[8];
            #pragma unroll
            for (int ds = 0; ds < 4; ds++) {
                vv[2*ds]   = *(const bf16x8*)&sV[(ds*8 + qd)*128 + lr*8];
                vv[2*ds+1] = *(const bf16x8*)&sV[(ds*8 + 4 + qd)*128 + lr*8];
            }
            #pragma unroll
            for (int p = 0; p < 2; p++) {
                bf16x8 p0 = *(const bf16x8*)&sP[w][p][lr*40 + qd*8];
                bf16x8 p1 = *(const bf16x8*)&sP[w][p][lr*40 + 32 + qd*8];
                #pragma unroll
                for (int ds = 0; ds < 4; ds++) {
                    O[p][ds] = MFMA16(p0, vv[2*ds],   O[p][ds]);
                    O[p][ds] = MFMA16(p1, vv[2*ds+1], O[p][ds]);
                }
            }
        }
        __syncthreads();
    }
    float* Op = Opart + (size_t)sc * TOKENS * E_;
    float* lp = lpart + (size_t)sc * TOKENS * H_;
    #pragma unroll
    for (int p = 0; p < 2; p++) {
        #pragma unroll
        for (int r = 0; r < 4; r++) {
            float s2 = lsum[p][r];
            s2 += __shfl_xor(s2, 1, 64);
            s2 += __shfl_xor(s2, 2, 64);
            s2 += __shfl_xor(s2, 4, 64);
            s2 += __shfl_xor(s2, 8, 64);
            lsum[p][r] = s2;
        }
        const int qb = q0 + p*64 + w*16 + qd*4;
        if (lr == 0) {
            #pragma unroll
            for (int r = 0; r < 4; r++)
                lp[(size_t)(b*S_ + qb + r) * H_ + h] = lsum[p][r];
        }
        #pragma unroll
        for (int ds = 0; ds < 4; ds++)
            #pragma unroll
            for (int r = 0; r < 4; r++)
                Op[(size_t)(b*S_ + qb + r) * E_ + h*64 + ds*16 + lr] = O[p][ds][r];
    }
}

// ---------------------------------------------------------------------------
// Combine split-S partials + gate + top2, one block per token.
// O = (O1+O2)/(l1+l2) -> attn_bf (bf16); gate logits in-register (fp32).
// ---------------------------------------------------------------------------
__global__ __launch_bounds__(256) void combine_gate(
    const float* __restrict__ Opart, const float* __restrict__ lpart,
    const float* __restrict__ gate_w, const float* __restrict__ gate_b,
    u16* __restrict__ attn_bf, float* __restrict__ gval, int* __restrict__ eidx)
{
    __shared__ float red[4][NE_];
    __shared__ float lg8[NE_];
    const int tok = blockIdx.x;
    const int t = threadIdx.x;
    const int d4 = t * 4;
    const int h = d4 >> 6;
    const float l = lpart[(size_t)tok*H_ + h] + lpart[(size_t)(TOKENS + tok)*H_ + h];
    const float inv = 1.f / l;
    const float4 o1 = *(const float4*)&Opart[(size_t)tok*E_ + d4];
    const float4 o2 = *(const float4*)&Opart[(size_t)(TOKENS + tok)*E_ + d4];
    float v[4] = {(o1.x+o2.x)*inv, (o1.y+o2.y)*inv, (o1.z+o2.z)*inv, (o1.w+o2.w)*inv};
    ushort4 H4 = {f2bf(v[0]), f2bf(v[1]), f2bf(v[2]), f2bf(v[3])};
    *(ushort4*)&attn_bf[(size_t)tok*E_ + d4] = H4;
    float pe[NE_];
    #pragma unroll
    for (int e = 0; e < NE_; e++) {
        const float4 g = *(const float4*)&gate_w[e*E_ + d4];
        pe[e] = v[0]*g.x + v[1]*g.y + v[2]*g.z + v[3]*g.w;
    }
    #pragma unroll
    for (int e = 0; e < NE_; e++) {
        #pragma unroll
        for (int off = 32; off >= 1; off >>= 1)
            pe[e] += __shfl_xor(pe[e], off, 64);
    }
    const int w = t >> 6;
    if ((t & 63) == 0) {
        #pragma unroll
        for (int e = 0; e < NE_; e++) red[w][e] = pe[e];
    }
    __syncthreads();
    if (t < NE_)
        lg8[t] = red[0][t] + red[1][t] + red[2][t] + red[3][t] + gate_b[t];
    __syncthreads();
    if (t == 0) {
        float lg[NE_];
        #pragma unroll
        for (int e = 0; e < NE_; e++) lg[e] = lg8[e];
        float m = lg[0];
        #pragma unroll
        for (int e = 1; e < NE_; e++) m = fmaxf(m, lg[e]);
        float ex[NE_], ssum = 0.f;
        #pragma unroll
        for (int e = 0; e < NE_; e++) { ex[e] = __expf(lg[e]-m); ssum += ex[e]; }
        const float invs = 1.f / ssum;
        int i0 = 0;
        #pragma unroll
        for (int e = 1; e < NE_; e++) if (lg[e] > lg[i0]) i0 = e;
        int i1 = (i0 == 0) ? 1 : 0;
        #pragma unroll
        for (int e = 0; e < NE_; e++) if (e != i0 && lg[e] > lg[i1]) i1 = e;
        eidx[tok*2]     = i0;
        gval[tok*2]     = ex[i0]*invs;
        eidx[tok*2 + 1] = i1;
        gval[tok*2 + 1] = ex[i1]*invs;
    }
}

// ---------------------------------------------------------------------------
// Build per-expert token lists: LDS histogram per block (512 entries),
// then 8 global atomics per block to reserve ranges, then scatter.
// ---------------------------------------------------------------------------
__global__ __launch_bounds__(256) void build_lists_kernel(
    const int* __restrict__ eidx, int* __restrict__ list, int* __restrict__ counts)
{
    __shared__ int lcnt[NE_], lbase[NE_];
    const int t = threadIdx.x;
    if (t < NE_) lcnt[t] = 0;
    __syncthreads();
    const int ent = blockIdx.x * 512 + t * 2;
    const int e0 = eidx[ent], e1 = eidx[ent + 1];
    const int p0 = atomicAdd(&lcnt[e0], 1);
    const int p1 = atomicAdd(&lcnt[e1], 1);
    __syncthreads();
    if (t < NE_) lbase[t] = atomicAdd(&counts[t], lcnt[t]);
    __syncthreads();
    list[e0 * TOKENS + lbase[e0] + p0] = ent;
    list[e1 * TOKENS + lbase[e1] + p1] = ent + 1;
}

// ---------------------------------------------------------------------------
// Gathered expert GEMM (bf16): sel[ent] = g * (attn[tok] @ ew[e]^T + eb[e])
// ---------------------------------------------------------------------------
__global__ __launch_bounds__(256,2) void gemm_expert(
    const u16* __restrict__ Abf, const u16* __restrict__ ewh,
    const float* __restrict__ eb, const int* __restrict__ list,
    const int* __restrict__ counts, const float* __restrict__ gval,
    u16* __restrict__ sel)
{
    const int e = blockIdx.z;
    const int cnt = counts[e];
    const int m0 = blockIdx.y * 128;
    if (m0 >= cnt) return;
    __shared__ __align__(16) u16 sA[128*32], sB[128*32];
    __shared__ int sEnt[128];
    const int t = threadIdx.x;
    if (t < 128) sEnt[t] = (m0 + t < cnt) ? list[e * TOKENS + m0 + t] : -1;
    __syncthreads();
    const int n0 = blockIdx.x * 128;
    const int lane = t & 63, w = t >> 6;
    const int wm = w >> 1, wn = w & 1;
    const int lr = lane & 15, qd = lane >> 4;
    const int e0 = sEnt[t >> 2], e1 = sEnt[64 + (t >> 2)];
    const u16* ga0 = Abf + (size_t)(e0 < 0 ? 0 : (e0 >> 1)) * E_ + (t & 3) * 8;
    const u16* ga1 = Abf + (size_t)(e1 < 0 ? 0 : (e1 >> 1)) * E_ + (t & 3) * 8;
    const u16* gb0 = ewh + (size_t)e * E_ * E_ + (size_t)(n0 + (t >> 2)) * E_ + (t & 3) * 8;
    const u16* gb1 = gb0 + 64 * E_;
    f32x4 acc[4][4] = {};
    for (int k0 = 0; k0 < E_; k0 += 32) {
        {
            const int l0 = (t & 192) * 16;
            const int l1 = (256 + (t & 192)) * 16;
            gl2lds16(ga0 + k0, (char*)sA + l0);
            gl2lds16(ga1 + k0, (char*)sA + l1);
            gl2lds16(gb0 + k0, (char*)sB + l0);
            gl2lds16(gb1 + k0, (char*)sB + l1);
        }
        __syncthreads();
        bf16x8 af[4], bfr[4];
        #pragma unroll
        for (int i = 0; i < 4; i++) {
            af[i]  = *(const bf16x8*)&sA[(wm*64 + i*16 + lr)*32 + qd*8];
            bfr[i] = *(const bf16x8*)&sB[(wn*64 + i*16 + lr)*32 + qd*8];
        }
        #pragma unroll
        for (int i = 0; i < 4; i++)
            #pragma unroll
            for (int j = 0; j < 4; j++)
                acc[i][j] = MFMA16(af[i], bfr[j], acc[i][j]);
        __syncthreads();
    }
    #pragma unroll
    for (int i = 0; i < 4; i++)
        #pragma unroll
        for (int r = 0; r < 4; r++) {
            const int local = wm*64 + i*16 + qd*4 + r;
            const int ent = sEnt[local];
            if (ent < 0) continue;
            const float g = gval[ent];
            #pragma unroll
            for (int j = 0; j < 4; j++) {
                const int col = n0 + wn*64 + j*16 + lr;
                sel[(size_t)ent * E_ + col] = f2bf((acc[i][j][r] + eb[e * E_ + col]) * g);
            }
        }
}

// ---------------------------------------------------------------------------
// moe[tok] = sel[tok*2] + sel[tok*2+1]  (bf16 in/out)
// ---------------------------------------------------------------------------
__global__ void combine_kernel(const u16* __restrict__ sel, u16* __restrict__ moe)
{
    const int g = blockIdx.x * 256 + threadIdx.x;
    const int tok = g >> 8;
    const int c = (g & 255) * 4;
    const u16* a = sel + (size_t)tok * 2048 + c;
    float o[4];
    #pragma unroll
    for (int j = 0; j < 4; j++) o[j] = bf2f(a[j]) + bf2f(a[1024 + j]);
    ushort4 R = {f2bf(o[0]), f2bf(o[1]), f2bf(o[2]), f2bf(o[3])};
    *(ushort4*)(moe + (size_t)tok * E_ + c) = R;
}

// ---------------------------------------------------------------------------
// FFN GEMM (bf16) + bias + fp32 residual -> fp32 out
// ---------------------------------------------------------------------------
__global__ __launch_bounds__(256,2) void gemm_ffn(
    const u16* __restrict__ Ah, const u16* __restrict__ Bh,
    const float* __restrict__ bias, const float* __restrict__ res,
    float* __restrict__ C)
{
    __shared__ __align__(16) u16 sA[128*32], sB[128*32];
    const int t = threadIdx.x;
    const int m0 = blockIdx.y * 128, n0 = blockIdx.x * 128;
    const int lane = t & 63, w = t >> 6;
    const int wm = w >> 1, wn = w & 1;
    const int lr = lane & 15, qd = lane >> 4;
    f32x4 acc[4][4] = {};
    const size_t gA = (size_t)(m0 + (t >> 2)) * E_ + (t & 3) * 8;
    const size_t gB = (size_t)(n0 + (t >> 2)) * E_ + (t & 3) * 8;
    for (int k0 = 0; k0 < E_; k0 += 32) {
        #pragma unroll
        for (int is = 0; is < 2; is++) {
            const int ldo = (is * 256 + (t & 192)) * 16;
            const size_t ro = (size_t)is * 64 * E_;
            gl2lds16(Ah + gA + ro + k0, (char*)sA + ldo);
            gl2lds16(Bh + gB + ro + k0, (char*)sB + ldo);
        }
        __syncthreads();
        bf16x8 af[4], bfr[4];
        #pragma unroll
        for (int i = 0; i < 4; i++) {
            af[i]  = *(const bf16x8*)&sA[(wm*64 + i*16 + lr)*32 + qd*8];
            bfr[i] = *(const bf16x8*)&sB[(wn*64 + i*16 + lr)*32 + qd*8];
        }
        #pragma unroll
        for (int i = 0; i < 4; i++)
            #pragma unroll
            for (int j = 0; j < 4; j++)
                acc[i][j] = MFMA16(af[i], bfr[j], acc[i][j]);
        __syncthreads();
    }
    #pragma unroll
    for (int i = 0; i < 4; i++)
        #pragma unroll
        for (int r = 0; r < 4; r++) {
            const int tok = m0 + wm*64 + i*16 + qd*4 + r;
            #pragma unroll
            for (int j = 0; j < 4; j++) {
                const int col = n0 + wn*64 + j*16 + lr;
                C[(size_t)tok * E_ + col] = acc[i][j][r] + bias[col] + res[(size_t)tok * E_ + col];
            }
        }
}

// ---------------------------------------------------------------------------
extern "C" void kernel_launch(void* const* d_in, const int* in_sizes, int n_in,
                              void* d_out, int out_size, void* d_ws, size_t ws_size,
                              hipStream_t stream) {
    const float* x      = (const float*)d_in[0];
    const float* q_w    = (const float*)d_in[1];
    const float* q_b    = (const float*)d_in[2];
    const float* k_w    = (const float*)d_in[3];
    const float* k_b    = (const float*)d_in[4];
    const float* v_w    = (const float*)d_in[5];
    const float* v_b    = (const float*)d_in[6];
    const float* gate_w = (const float*)d_in[7];
    const float* gate_b = (const float*)d_in[8];
    const float* ew     = (const float*)d_in[9];
    const float* eb     = (const float*)d_in[10];
    const float* ffn_w  = (const float*)d_in[11];
    const float* ffn_b  = (const float*)d_in[12];
    float* out = (float*)d_out;

    char* p = (char*)d_ws;
    auto alloc = [&](size_t bytes) { char* r = p; p += (bytes + 255) & ~(size_t)255; return r; };
    u16* xh   = (u16*)alloc((size_t)TOKENS*E_*2);
    u16* qwh  = (u16*)alloc((size_t)E_*E_*2);
    u16* kwh  = (u16*)alloc((size_t)E_*E_*2);
    u16* vwh  = (u16*)alloc((size_t)E_*E_*2);
    u16* fwh  = (u16*)alloc((size_t)E_*E_*2);
    u16* ewh  = (u16*)alloc((size_t)NE_*E_*E_*2);
    u16* Qhb  = (u16*)alloc((size_t)TOKENS*E_*2);
    u16* Khb  = (u16*)alloc((size_t)TOKENS*E_*2);
    u16* Vtb  = (u16*)alloc((size_t)TOKENS*E_*2);
    u16* abf  = (u16*)alloc((size_t)TOKENS*E_*2);
    float* Opart = (float*)alloc((size_t)2*TOKENS*E_*4);
    float* lpart = (float*)alloc((size_t)2*TOKENS*H_*4);
    u16* selb = (u16*)alloc((size_t)2*TOKENS*E_*2);
    u16* moeb = (u16*)alloc((size_t)TOKENS*E_*2);
    float2* rtab = (float2*)alloc((size_t)S_*32*8);
    float* gvl = (float*)alloc((size_t)2*TOKENS*4);
    int*   eix = (int*)alloc((size_t)2*TOKENS*4);
    int*   lst = (int*)alloc((size_t)NE_*TOKENS*4);
    int*   cnt = (int*)alloc(256);

    hipMemsetAsync(cnt, 0, 256, stream);

    rope_tab_kernel<<<S_*32/256, 256, 0, stream>>>(rtab);
    cvt_all_k<<<16384, 256, 0, stream>>>(x, q_w, k_w, v_w, ffn_w, ew,
                                         xh, qwh, kwh, vwh, fwh, ewh);

    gemm_qkv<<<dim3(8,32,3), 256, 0, stream>>>(xh, qwh, kwh, vwh,
                                               q_b, k_b, v_b, rtab,
                                               Qhb, Khb, Vtb);

    attn_kernel<<<dim3(16,16,4), 256, 0, stream>>>(Qhb, Khb, Vtb, Opart, lpart);

    combine_gate<<<TOKENS, 256, 0, stream>>>(Opart, lpart, gate_w, gate_b,
                                             abf, gvl, eix);
    build_lists_kernel<<<TOKENS/256, 256, 0, stream>>>(eix, lst, cnt);
    gemm_expert<<<dim3(8,32,8), 256, 0, stream>>>(abf, ewh, eb, lst, cnt, gvl, selb);
    combine_kernel<<<4096, 256, 0, stream>>>(selb, moeb);
    gemm_ffn<<<dim3(8,32), 256, 0, stream>>>(moeb, fwh, ffn_b, x, out);
}